// Round 1
// baseline (183.074 us; speedup 1.0000x reference)
//
#include <hip/hip_runtime.h>

using u16 = unsigned short;
using u32 = unsigned int;

#define ALPHA 0.2f

typedef __bf16 bf16x8 __attribute__((ext_vector_type(8)));
typedef float f32x4 __attribute__((ext_vector_type(4)));

__device__ __forceinline__ u16 f2bf(float f) {
  u32 u = __builtin_bit_cast(u32, f);
  u += 0x7FFFu + ((u >> 16) & 1u);   // round-to-nearest-even
  return (u16)(u >> 16);
}
__device__ __forceinline__ float bf2f(u16 h) {
  u32 u = ((u32)h) << 16;
  return __builtin_bit_cast(float, u);
}
__device__ __forceinline__ void gload_lds16(const void* g, void* l) {
  __builtin_amdgcn_global_load_lds((__attribute__((address_space(1))) void*)g,
                                   (__attribute__((address_space(3))) void*)l,
                                   16, 0, 0);
}

// ---------- cast x f32 -> bf16 (8 elems/thread) ----------
__global__ __launch_bounds__(256) void k_cast_x(const float* __restrict__ x, u16* __restrict__ xbf) {
  size_t i = (size_t)blockIdx.x * 256 + threadIdx.x;   // 0..1048575
  const float4* src = reinterpret_cast<const float4*>(x + i * 8);
  float4 f0 = src[0], f1 = src[1];
  uint4 o;
  o.x = (u32)f2bf(f0.x) | ((u32)f2bf(f0.y) << 16);
  o.y = (u32)f2bf(f0.z) | ((u32)f2bf(f0.w) << 16);
  o.z = (u32)f2bf(f1.x) | ((u32)f2bf(f1.y) << 16);
  o.w = (u32)f2bf(f1.z) | ((u32)f2bf(f1.w) << 16);
  *reinterpret_cast<uint4*>(xbf + i * 8) = o;
}

// ---------- cast+transpose W: wbt[n][k] = bf16(W[k][n]) ----------
__global__ __launch_bounds__(256) void k_cast_wT(const float* __restrict__ W, u16* __restrict__ wbt) {
  int idx = blockIdx.x * 256 + threadIdx.x;  // 0..262143
  int k = idx >> 9, n = idx & 511;
  wbt[n * 512 + k] = f2bf(W[idx]);
}

// ---------- gemm1: hbf[m][f] = bf16( x[m][:] . W[:][f] ), M=16384 K=512 N=512 ----------
// 128x128 tile, BK=32, 4 waves (each 64x64 -> 4x4 MFMA tiles), global_load_lds staging.
__global__ __launch_bounds__(256) void k_gemm1(const u16* __restrict__ xbf, const u16* __restrict__ wbt,
                                               u16* __restrict__ hbf) {
  __shared__ u16 lds_a[128 * 32];
  __shared__ u16 lds_b[128 * 32];
  const int tid = threadIdx.x;
  const int lane = tid & 63;
  const int w = tid >> 6;
  const int tile_n = blockIdx.x & 3;
  const int tile_m = blockIdx.x >> 2;
  const int row0 = tile_m * 128;
  const int col0 = tile_n * 128;
  const int wr = w >> 1, wc = w & 1;

  f32x4 acc[4][4];
#pragma unroll
  for (int mi = 0; mi < 4; ++mi)
#pragma unroll
    for (int ni = 0; ni < 4; ++ni) acc[mi][ni] = (f32x4){0.f, 0.f, 0.f, 0.f};

  const int srow = tid >> 2;       // 0..63
  const int sk8 = (tid & 3) * 8;

#pragma unroll 1
  for (int kt = 0; kt < 16; ++kt) {
    const int k0 = kt * 32;
#pragma unroll
    for (int s = 0; s < 2; ++s) {
      gload_lds16(xbf + (size_t)(row0 + s * 64 + srow) * 512 + k0 + sk8,
                  lds_a + s * 2048 + w * 512);
      gload_lds16(wbt + (size_t)(col0 + s * 64 + srow) * 512 + k0 + sk8,
                  lds_b + s * 2048 + w * 512);
    }
    __syncthreads();
    bf16x8 af[4], bfr[4];
#pragma unroll
    for (int mi = 0; mi < 4; ++mi)
      af[mi] = *reinterpret_cast<const bf16x8*>(lds_a + (wr * 64 + mi * 16 + (lane & 15)) * 32 + (lane >> 4) * 8);
#pragma unroll
    for (int ni = 0; ni < 4; ++ni)
      bfr[ni] = *reinterpret_cast<const bf16x8*>(lds_b + (wc * 64 + ni * 16 + (lane & 15)) * 32 + (lane >> 4) * 8);
#pragma unroll
    for (int mi = 0; mi < 4; ++mi)
#pragma unroll
      for (int ni = 0; ni < 4; ++ni)
        acc[mi][ni] = __builtin_amdgcn_mfma_f32_16x16x32_bf16(af[mi], bfr[ni], acc[mi][ni], 0, 0, 0);
    __syncthreads();
  }

  const int crow = (lane >> 4) * 4;
  const int ccol = lane & 15;
#pragma unroll
  for (int mi = 0; mi < 4; ++mi)
#pragma unroll
    for (int ni = 0; ni < 4; ++ni) {
      const int grow = row0 + wr * 64 + mi * 16 + crow;
      const int gcol = col0 + wc * 64 + ni * 16 + ccol;
#pragma unroll
      for (int r = 0; r < 4; ++r)
        hbf[(size_t)(grow + r) * 512 + gcol] = f2bf(acc[mi][ni][r]);
    }
}

// ---------- score: s1[row]=h.a1, s2[row]=h.a2 (one wave per row) ----------
__global__ __launch_bounds__(256) void k_score(const u16* __restrict__ hbf, const float* __restrict__ a,
                                               float* __restrict__ s1, float* __restrict__ s2) {
  const int lane = threadIdx.x & 63;
  const int w = threadIdx.x >> 6;
  const int row = blockIdx.x * 4 + w;
  const u16* hp = hbf + (size_t)row * 512 + lane * 8;
  uint4 hv = *reinterpret_cast<const uint4*>(hp);
  const float* a1 = a + lane * 8;
  const float* a2 = a + 512 + lane * 8;
  u32 words[4] = {hv.x, hv.y, hv.z, hv.w};
  float d1 = 0.f, d2 = 0.f;
#pragma unroll
  for (int j = 0; j < 8; ++j) {
    float h = bf2f((u16)(words[j >> 1] >> ((j & 1) * 16)));
    d1 += h * a1[j];
    d2 += h * a2[j];
  }
#pragma unroll
  for (int off = 32; off > 0; off >>= 1) {
    d1 += __shfl_down(d1, off);
    d2 += __shfl_down(d2, off);
  }
  if (lane == 0) { s1[row] = d1; s2[row] = d2; }
}

// ---------- per-batch max of s2 ----------
__global__ __launch_bounds__(256) void k_s2max(const float* __restrict__ s2, float* __restrict__ s2m) {
  __shared__ float red[256];
  const int b = blockIdx.x, t = threadIdx.x;
  float m = -INFINITY;
  for (int i = t; i < 1024; i += 256) m = fmaxf(m, s2[b * 1024 + i]);
  red[t] = m;
  __syncthreads();
  if (t < 64) {
    m = fmaxf(fmaxf(red[t], red[t + 64]), fmaxf(red[t + 128], red[t + 192]));
    for (int off = 32; off > 0; off >>= 1) m = fmaxf(m, __shfl_down(m, off));
    if (t == 0) s2m[b] = m;
  }
}

// ---------- transpose hbf (b,1024,512) -> hbt (b,512,1024), 64x64 LDS tiles ----------
__global__ __launch_bounds__(256) void k_transpose(const u16* __restrict__ hbf, u16* __restrict__ hbt) {
  __shared__ u16 tile[64 * 80];   // pad to 80 (160B rows, 16B-aligned)
  const int t = threadIdx.x;
  const int b = blockIdx.x >> 7;
  const int mt = (blockIdx.x >> 3) & 15;
  const int ft = blockIdx.x & 7;
  const int m0 = mt * 64, f0 = ft * 64;
#pragma unroll
  for (int s = 0; s < 2; ++s) {
    const int m = (t + s * 256) >> 3;
    const int f8 = (t & 7) * 8;
    uint4 v = *reinterpret_cast<const uint4*>(hbf + ((size_t)(b * 1024 + m0 + m) * 512 + f0 + f8));
    *reinterpret_cast<uint4*>(tile + m * 80 + f8) = v;
  }
  __syncthreads();
#pragma unroll
  for (int s = 0; s < 2; ++s) {
    const int f = (t + s * 256) >> 3;
    const int m8 = (t & 7) * 8;
    u32 wd[4];
#pragma unroll
    for (int jj = 0; jj < 4; ++jj) {
      u16 lo = tile[(m8 + 2 * jj) * 80 + f];
      u16 hi = tile[(m8 + 2 * jj + 1) * 80 + f];
      wd[jj] = (u32)lo | ((u32)hi << 16);
    }
    uint4 o = {wd[0], wd[1], wd[2], wd[3]};
    *reinterpret_cast<uint4*>(hbt + ((size_t)(b * 512 + f0 + f) * 1024 + m0 + m8)) = o;
  }
}

// ---------- attn: per (b, 32-row tile): P = softmax(lrelu(s1+s2)), out = elu(P@h + beta*h) ----------
__global__ __launch_bounds__(512) void k_attn(const u16* __restrict__ hbt, const float* __restrict__ s1g,
                                              const float* __restrict__ s2g, const float* __restrict__ s2mg,
                                              const float* __restrict__ betag, float* __restrict__ out) {
  __shared__ float s2_lds[1024];
  __shared__ float s1_lds[32];
  __shared__ float mx_lds[32];
  __shared__ float inv_lds[32];
  __shared__ u16 p_lds[32 * 32];
  const int t = threadIdx.x;
  const int lane = t & 63;
  const int w = t >> 6;
  const int b = blockIdx.x >> 5;
  const int n0 = (blockIdx.x & 31) * 32;

  s2_lds[t] = s2g[b * 1024 + t];
  s2_lds[t + 512] = s2g[b * 1024 + t + 512];
  if (t < 32) {
    float s1v = s1g[b * 1024 + n0 + t];
    s1_lds[t] = s1v;
    float e = s1v + s2mg[b];
    mx_lds[t] = e > 0.f ? e : ALPHA * e;   // lrelu monotone => row max
  }
  __syncthreads();

  { // exact fp32 denominators; fold 1/den into P
    const int n = t >> 4, l16 = t & 15;
    const float s1v = s1_lds[n], mx = mx_lds[n];
    float sum = 0.f;
    for (int m = l16; m < 1024; m += 16) {
      float e = s1v + s2_lds[m];
      float v = e > 0.f ? e : ALPHA * e;
      sum += __expf(v - mx);
    }
    sum += __shfl_xor(sum, 1);
    sum += __shfl_xor(sum, 2);
    sum += __shfl_xor(sum, 4);
    sum += __shfl_xor(sum, 8);
    if (l16 == 0) inv_lds[n] = 1.0f / sum;
  }
  __syncthreads();

  const int wr = w >> 2, wc = w & 3;      // wave covers rows n0+wr*16..+16, cols wc*128..+128
  f32x4 acc[8];
#pragma unroll
  for (int c = 0; c < 8; ++c) acc[c] = (f32x4){0.f, 0.f, 0.f, 0.f};

  const u16* hb = hbt + (size_t)b * 512 * 1024;
  const int pn = t >> 4;                  // P-entry row for this thread (idx=2t)
  const int pm = (2 * t) & 31;
  const float ps1 = s1_lds[pn], pmx = mx_lds[pn], pinv = inv_lds[pn];

#pragma unroll 1
  for (int mt = 0; mt < 32; ++mt) {
    const int m0 = mt * 32;
    __syncthreads();                      // prev iteration's A-frag reads done
    {
      float e0 = ps1 + s2_lds[m0 + pm];
      float e1 = ps1 + s2_lds[m0 + pm + 1];
      float v0 = e0 > 0.f ? e0 : ALPHA * e0;
      float v1 = e1 > 0.f ? e1 : ALPHA * e1;
      u32 p0 = f2bf(__expf(v0 - pmx) * pinv);
      u32 p1 = f2bf(__expf(v1 - pmx) * pinv);
      *reinterpret_cast<u32*>(p_lds + 2 * t) = p0 | (p1 << 16);
    }
    __syncthreads();
    bf16x8 af = *reinterpret_cast<const bf16x8*>(p_lds + (wr * 16 + (lane & 15)) * 32 + (lane >> 4) * 8);
#pragma unroll
    for (int c = 0; c < 8; ++c) {
      const int col = wc * 128 + c * 16 + (lane & 15);
      bf16x8 bv = *reinterpret_cast<const bf16x8*>(hb + (size_t)col * 1024 + m0 + (lane >> 4) * 8);
      acc[c] = __builtin_amdgcn_mfma_f32_16x16x32_bf16(af, bv, acc[c], 0, 0, 0);
    }
  }

  const float beta = betag[0];
  const int rbase = n0 + wr * 16 + (lane >> 4) * 4;
#pragma unroll
  for (int c = 0; c < 8; ++c) {
    const int col = wc * 128 + c * 16 + (lane & 15);
    const u16* hp = hb + (size_t)col * 1024 + rbase;
    u32 h01 = *reinterpret_cast<const u32*>(hp);
    u32 h23 = *reinterpret_cast<const u32*>(hp + 2);
    float hv[4] = {bf2f((u16)h01), bf2f((u16)(h01 >> 16)), bf2f((u16)h23), bf2f((u16)(h23 >> 16))};
#pragma unroll
    for (int r = 0; r < 4; ++r) {
      float xv = acc[c][r] + beta * hv[r];
      out[((size_t)b * 1024 + rbase + r) * 512 + col] = xv > 0.f ? xv : expm1f(xv);
    }
  }
}

extern "C" void kernel_launch(void* const* d_in, const int* in_sizes, int n_in,
                              void* d_out, int out_size, void* d_ws, size_t ws_size,
                              hipStream_t stream) {
  const float* x = (const float*)d_in[0];
  const float* W = (const float*)d_in[1];
  const float* a = (const float*)d_in[2];
  const float* beta = (const float*)d_in[3];
  float* out = (float*)d_out;

  // workspace layout (~33.7 MiB): [0,16M) xbf, reused as hbt after gemm1;
  // [16M,32M) hbf; [32M,+512K) wbt; then s1/s2/s2max.
  char* ws = (char*)d_ws;
  u16* xbf = (u16*)ws;
  u16* hbt = (u16*)ws;                         // alias: transpose runs after gemm1
  u16* hbf = (u16*)(ws + (16u << 20));
  u16* wbt = (u16*)(ws + (32u << 20));
  float* s1 = (float*)(ws + (32u << 20) + (512u << 10));
  float* s2 = (float*)(ws + (32u << 20) + (512u << 10) + (64u << 10));
  float* s2m = (float*)(ws + (32u << 20) + (512u << 10) + (128u << 10));

  k_cast_x<<<4096, 256, 0, stream>>>(x, xbf);
  k_cast_wT<<<1024, 256, 0, stream>>>(W, wbt);
  k_gemm1<<<512, 256, 0, stream>>>(xbf, wbt, hbf);
  k_score<<<4096, 256, 0, stream>>>(hbf, a, s1, s2);
  k_s2max<<<16, 256, 0, stream>>>(s2, s2m);
  k_transpose<<<2048, 256, 0, stream>>>(hbf, hbt);
  k_attn<<<512, 512, 0, stream>>>(hbt, s1, s2, s2m, beta, out);
}

// Round 2
// 128.494 us; speedup vs baseline: 1.4248x; 1.4248x over previous
//
#include <hip/hip_runtime.h>

using u16 = unsigned short;
using u32 = unsigned int;

#define ALPHA 0.2f
#define LOG2E 1.4426950408889634f

typedef __bf16 bf16x8 __attribute__((ext_vector_type(8)));
typedef float f32x4 __attribute__((ext_vector_type(4)));
typedef float f32x16 __attribute__((ext_vector_type(16)));

__device__ __forceinline__ u16 f2bf(float f) {
  u32 u = __builtin_bit_cast(u32, f);
  u += 0x7FFFu + ((u >> 16) & 1u);   // RTNE
  return (u16)(u >> 16);
}
__device__ __forceinline__ float bf2f(u16 h) {
  u32 u = ((u32)h) << 16;
  return __builtin_bit_cast(float, u);
}
__device__ __forceinline__ void gload_lds16(const void* g, void* l) {
  __builtin_amdgcn_global_load_lds((__attribute__((address_space(1))) void*)g,
                                   (__attribute__((address_space(3))) void*)l,
                                   16, 0, 0);
}

// ---------- cast+transpose W: wbt[n][k] = bf16(W[k][n]) ----------
__global__ __launch_bounds__(256) void k_cast_wT(const float* __restrict__ W, u16* __restrict__ wbt) {
  int idx = blockIdx.x * 256 + threadIdx.x;  // 0..262143
  int k = idx >> 9, n = idx & 511;
  wbt[n * 512 + k] = f2bf(W[idx]);
}

// ---------- gemm1: h = x @ W  (M=16384,K=512,N=512), f32 x staged directly.
// 128x256 tile, 8 waves (4 rowbands x 2 colgroups), mfma_32x32x16_bf16.
// Epilogue: LDS transpose -> writes hbf [m][f] AND hbt [b][f][m].
__global__ __launch_bounds__(512, 2) void k_gemm1(const float* __restrict__ x, const u16* __restrict__ wbt,
                                                  u16* __restrict__ hbf, u16* __restrict__ hbt) {
  // union: staging (lA 16KB f32 + lB 16KB bf16) vs epilogue transpose tile (128x264 u16 = 67.6KB)
  __shared__ __attribute__((aligned(16))) char ldsraw[128 * 264 * 2];
  float* lA = (float*)ldsraw;                 // [8 slots][128 rows][4 f32]
  u16* lB = (u16*)(ldsraw + 16384);           // [4 kgslots][256 cols][8 bf16]
  u16* lT = (u16*)ldsraw;                     // [128 rows][264 cols]

  const int t = threadIdx.x;
  const int lane = t & 63;
  const int w = t >> 6;
  const int l31 = lane & 31, lhi = lane >> 5;
  const int rb = w >> 1, cg = w & 1;
  const int tile_m = blockIdx.x >> 1;
  const int row0 = tile_m * 128;
  const int col0 = (blockIdx.x & 1) * 256;

  f32x16 acc[4];
#pragma unroll
  for (int ct = 0; ct < 4; ++ct)
#pragma unroll
    for (int r = 0; r < 16; ++r) acc[ct][r] = 0.f;

  const int arow = rb * 32 + l31;

#pragma unroll 1
  for (int kt = 0; kt < 16; ++kt) {
    const int k0 = kt * 32;
    // stage A (f32): 1024 granules of 16B, 2 rounds
#pragma unroll
    for (int s = 0; s < 2; ++s) {
      int G = s * 512 + w * 64 + lane;
      int slot = G >> 7, row = G & 127;
      gload_lds16(x + (size_t)(row0 + row) * 512 + k0 + slot * 4,
                  (char*)lA + (size_t)(s * 512 + w * 64) * 16);
    }
    // stage B (bf16): 1024 granules, 2 rounds
#pragma unroll
    for (int s = 0; s < 2; ++s) {
      int G = s * 512 + w * 64 + lane;
      int kg = G >> 8, col = G & 255;
      gload_lds16(wbt + (size_t)(col0 + col) * 512 + k0 + kg * 8,
                  (char*)lB + (size_t)(s * 512 + w * 64) * 16);
    }
    __syncthreads();
#pragma unroll
    for (int ks = 0; ks < 2; ++ks) {
      const int slot = ks * 4 + lhi * 2;
      f32x4 fa0 = *reinterpret_cast<const f32x4*>(&lA[(slot * 128 + arow) * 4]);
      f32x4 fa1 = *reinterpret_cast<const f32x4*>(&lA[((slot + 1) * 128 + arow) * 4]);
      bf16x8 af;
#pragma unroll
      for (int j = 0; j < 4; ++j) {
        af[j] = (__bf16)fa0[j];
        af[j + 4] = (__bf16)fa1[j];
      }
#pragma unroll
      for (int ct = 0; ct < 4; ++ct) {
        const int colv = cg * 128 + ct * 32 + l31;
        bf16x8 bv = *reinterpret_cast<const bf16x8*>(&lB[((ks * 2 + lhi) * 256 + colv) * 8]);
        acc[ct] = __builtin_amdgcn_mfma_f32_32x32x16_bf16(af, bv, acc[ct], 0, 0, 0);
      }
    }
    __syncthreads();
  }

  // epilogue: C frags -> lT (bf16), then coalesced writes of hbf and hbt
#pragma unroll
  for (int ct = 0; ct < 4; ++ct) {
    const int colv = cg * 128 + ct * 32 + l31;
#pragma unroll
    for (int r = 0; r < 16; ++r) {
      int row = rb * 32 + (r & 3) + 8 * (r >> 2) + 4 * lhi;
      lT[row * 264 + colv] = f2bf(acc[ct][r]);
    }
  }
  __syncthreads();
  // hbf: [row][col] 16B chunks
#pragma unroll
  for (int rsub = 0; rsub < 8; ++rsub) {
    int G = rsub * 512 + t;
    int row = G >> 5, g = G & 31;
    uint4 v = *reinterpret_cast<const uint4*>(&lT[row * 264 + g * 8]);
    *reinterpret_cast<uint4*>(&hbf[(size_t)(row0 + row) * 512 + col0 + g * 8]) = v;
  }
  // hbt: [b][f][m] — lanes span consecutive cols (conflict-free LDS reads)
  const int bb = row0 >> 10;
  const int nb = row0 & 1023;
#pragma unroll
  for (int rsub = 0; rsub < 8; ++rsub) {
    int G = rsub * 512 + t;
    int col = G & 255;
    int rc = ((rsub * 2) + (t >> 8)) & 15;   // 8 rows per chunk
    u32 wd[4];
#pragma unroll
    for (int jj = 0; jj < 4; ++jj) {
      u16 lo = lT[(rc * 8 + 2 * jj) * 264 + col];
      u16 hi = lT[(rc * 8 + 2 * jj + 1) * 264 + col];
      wd[jj] = (u32)lo | ((u32)hi << 16);
    }
    uint4 o = {wd[0], wd[1], wd[2], wd[3]};
    *reinterpret_cast<uint4*>(&hbt[(size_t)(bb * 512 + col0 + col) * 1024 + nb + rc * 8]) = o;
  }
}

// ---------- score: s1L[row]=h.a1*log2e, s2L[row]=h.a2*log2e (one wave per row) ----------
__global__ __launch_bounds__(256) void k_score(const u16* __restrict__ hbf, const float* __restrict__ a,
                                               float* __restrict__ s1L, float* __restrict__ s2L) {
  const int lane = threadIdx.x & 63;
  const int w = threadIdx.x >> 6;
  const int row = blockIdx.x * 4 + w;
  const u16* hp = hbf + (size_t)row * 512 + lane * 8;
  uint4 hv = *reinterpret_cast<const uint4*>(hp);
  const float* a1 = a + lane * 8;
  const float* a2 = a + 512 + lane * 8;
  u32 words[4] = {hv.x, hv.y, hv.z, hv.w};
  float d1 = 0.f, d2 = 0.f;
#pragma unroll
  for (int j = 0; j < 8; ++j) {
    float h = bf2f((u16)(words[j >> 1] >> ((j & 1) * 16)));
    d1 += h * a1[j];
    d2 += h * a2[j];
  }
#pragma unroll
  for (int off = 32; off > 0; off >>= 1) {
    d1 += __shfl_down(d1, off);
    d2 += __shfl_down(d2, off);
  }
  if (lane == 0) { s1L[row] = d1 * LOG2E; s2L[row] = d2 * LOG2E; }
}

// ---------- denom: inv[row] = 1 / sum_m exp2(lrelu-scaled e) ----------
__global__ __launch_bounds__(256) void k_denom(const float* __restrict__ s1Lg, const float* __restrict__ s2Lg,
                                               float* __restrict__ invg) {
  const int lane = threadIdx.x & 63;
  const int w = threadIdx.x >> 6;
  const int row = blockIdx.x * 4 + w;
  const int b = row >> 10;
  const float s1v = s1Lg[row];
  const float* s2p = s2Lg + ((size_t)b << 10);
  float sum = 0.f;
#pragma unroll
  for (int i = 0; i < 16; ++i) {
    float e = s1v + s2p[i * 64 + lane];
    sum += exp2f(fmaxf(e, ALPHA * e));
  }
#pragma unroll
  for (int off = 32; off > 0; off >>= 1) sum += __shfl_xor(sum, off);
  if (lane == 0) invg[row] = 1.0f / sum;
}

// ---------- attn: barrier-free PV GEMM with in-register P via rank-1 tables ----------
__global__ __launch_bounds__(512, 2) void k_attn(const u16* __restrict__ hbt, const float* __restrict__ s1Lg,
                                                 const float* __restrict__ s2Lg, const float* __restrict__ invg,
                                                 const float* __restrict__ betag, float* __restrict__ out) {
  __shared__ __attribute__((aligned(16))) float s2_l[1024];
  __shared__ __attribute__((aligned(16))) float e1_l[1024];
  __shared__ __attribute__((aligned(16))) float e2_l[1024];
  const int t = threadIdx.x;
  const int lane = t & 63;
  const int w = t >> 6;
  const int l31 = lane & 31, lhi = lane >> 5;

  // XCD swizzle: all 16 blocks of a batch land on the same XCD (2 batches/XCD L2)
  const int B = blockIdx.x;
  const int b = (B & 7) * 2 + ((B >> 3) & 1);
  const int j = B >> 4;              // [0,16)
  const int n0 = (j >> 1) * 128;
  const int c0 = (j & 1) * 256;

  for (int i = t; i < 1024; i += 512) {
    float v = s2Lg[b * 1024 + i];
    s2_l[i] = v;
    e1_l[i] = exp2f(v);
    e2_l[i] = exp2f(ALPHA * v);
  }
  __syncthreads();

  const int rb = w >> 1, cg = w & 1;
  const int myrow = n0 + rb * 32 + l31;
  const float s1v = s1Lg[b * 1024 + myrow];
  const float c1 = exp2f(s1v), c2 = exp2f(ALPHA * s1v);
  const u16* hb = hbt + (size_t)b * 512 * 1024;

  const u16* hcol[4];
#pragma unroll
  for (int ct = 0; ct < 4; ++ct) {
    const int colv = c0 + cg * 128 + ct * 32 + l31;
    hcol[ct] = hb + (size_t)colv * 1024 + lhi * 8;
  }

  f32x16 acc[4];
#pragma unroll
  for (int ct = 0; ct < 4; ++ct)
#pragma unroll
    for (int r = 0; r < 16; ++r) acc[ct][r] = 0.f;

#pragma unroll 4
  for (int step = 0; step < 64; ++step) {
    const int mo = step * 16 + lhi * 8;
    f32x4 sa = *reinterpret_cast<const f32x4*>(&s2_l[mo]);
    f32x4 sb = *reinterpret_cast<const f32x4*>(&s2_l[mo + 4]);
    f32x4 ea = *reinterpret_cast<const f32x4*>(&e1_l[mo]);
    f32x4 eb = *reinterpret_cast<const f32x4*>(&e1_l[mo + 4]);
    f32x4 fa = *reinterpret_cast<const f32x4*>(&e2_l[mo]);
    f32x4 fb = *reinterpret_cast<const f32x4*>(&e2_l[mo + 4]);
    bf16x8 af;
#pragma unroll
    for (int q = 0; q < 4; ++q) {
      float p0 = (s1v + sa[q] > 0.f) ? c1 * ea[q] : c2 * fa[q];
      float p1 = (s1v + sb[q] > 0.f) ? c1 * eb[q] : c2 * fb[q];
      af[q] = (__bf16)p0;
      af[q + 4] = (__bf16)p1;
    }
#pragma unroll
    for (int ct = 0; ct < 4; ++ct) {
      bf16x8 bv = *reinterpret_cast<const bf16x8*>(hcol[ct] + step * 16);
      acc[ct] = __builtin_amdgcn_mfma_f32_32x32x16_bf16(af, bv, acc[ct], 0, 0, 0);
    }
  }

  const float beta = betag[0];
  const float* invb = invg + b * 1024;
#pragma unroll
  for (int ct = 0; ct < 4; ++ct) {
    const int colv = c0 + cg * 128 + ct * 32 + l31;
    const u16* hp = hb + (size_t)colv * 1024;
#pragma unroll
    for (int rg = 0; rg < 4; ++rg) {
      const int rowb = n0 + rb * 32 + rg * 8 + lhi * 4;
      f32x4 iv = *reinterpret_cast<const f32x4*>(&invb[rowb]);
      u32 h01 = *reinterpret_cast<const u32*>(&hp[rowb]);
      u32 h23 = *reinterpret_cast<const u32*>(&hp[rowb + 2]);
      float hv[4] = {bf2f((u16)h01), bf2f((u16)(h01 >> 16)), bf2f((u16)h23), bf2f((u16)(h23 >> 16))};
#pragma unroll
      for (int q = 0; q < 4; ++q) {
        float xv = acc[ct][rg * 4 + q] * iv[q] + beta * hv[q];
        out[((size_t)b * 1024 + rowb + q) * 512 + colv] = xv > 0.f ? xv : __expf(xv) - 1.0f;
      }
    }
  }
}

extern "C" void kernel_launch(void* const* d_in, const int* in_sizes, int n_in,
                              void* d_out, int out_size, void* d_ws, size_t ws_size,
                              hipStream_t stream) {
  const float* x = (const float*)d_in[0];
  const float* W = (const float*)d_in[1];
  const float* a = (const float*)d_in[2];
  const float* beta = (const float*)d_in[3];
  float* out = (float*)d_out;

  // ws layout: hbf [0,16M), hbt [16M,32M), wbt [32M,+512K), s1L/s2L/inv +64K each
  char* ws = (char*)d_ws;
  u16* hbf = (u16*)ws;
  u16* hbt = (u16*)(ws + (16u << 20));
  u16* wbt = (u16*)(ws + (32u << 20));
  float* s1L = (float*)(ws + (32u << 20) + (512u << 10));
  float* s2L = (float*)(ws + (32u << 20) + (576u << 10));
  float* inv = (float*)(ws + (32u << 20) + (640u << 10));

  k_cast_wT<<<1024, 256, 0, stream>>>(W, wbt);
  k_gemm1<<<256, 512, 0, stream>>>(x, wbt, hbf, hbt);
  k_score<<<4096, 256, 0, stream>>>(hbf, a, s1L, s2L);
  k_denom<<<4096, 256, 0, stream>>>(s1L, s2L, inv);
  k_attn<<<256, 512, 0, stream>>>(hbt, s1L, s2L, inv, beta, out);
}

// Round 3
// 98.169 us; speedup vs baseline: 1.8649x; 1.3089x over previous
//
#include <hip/hip_runtime.h>

using u16 = unsigned short;
using u32 = unsigned int;

#define ALPHA 0.2f
#define LOG2E 1.4426950408889634f

typedef __bf16 bf16x8 __attribute__((ext_vector_type(8)));
typedef float f32x4 __attribute__((ext_vector_type(4)));
typedef float f32x16 __attribute__((ext_vector_type(16)));

__device__ __forceinline__ u16 f2bf(float f) {
  u32 u = __builtin_bit_cast(u32, f);
  u += 0x7FFFu + ((u >> 16) & 1u);   // RTNE
  return (u16)(u >> 16);
}
__device__ __forceinline__ float bf2f(u16 h) {
  u32 u = ((u32)h) << 16;
  return __builtin_bit_cast(float, u);
}
__device__ __forceinline__ void gload_lds16(const void* g, void* l) {
  __builtin_amdgcn_global_load_lds((__attribute__((address_space(1))) void*)g,
                                   (__attribute__((address_space(3))) void*)l,
                                   16, 0, 0);
}

// ---------- cast+transpose W: wbt[n][k] = bf16(W[k][n]) ----------
__global__ __launch_bounds__(256) void k_cast_wT(const float* __restrict__ W, u16* __restrict__ wbt) {
  int idx = blockIdx.x * 256 + threadIdx.x;  // 0..262143
  int k = idx >> 9, n = idx & 511;
  wbt[n * 512 + k] = f2bf(W[idx]);
}

// ---------- gemm1: h = x @ W  (M=16384,K=512,N=512), f32 x staged directly.
// 128x256 tile, 8 waves (4 rowbands x 2 colgroups), mfma_32x32x16_bf16.
// Epilogue: LDS transpose -> writes hbf [m][f] AND hbt [b][f][m].
__global__ __launch_bounds__(512, 2) void k_gemm1(const float* __restrict__ x, const u16* __restrict__ wbt,
                                                  u16* __restrict__ hbf, u16* __restrict__ hbt) {
  // union: staging (lA 16KB f32 + lB 16KB bf16) vs epilogue transpose tile (128x264 u16 = 67.6KB)
  __shared__ __attribute__((aligned(16))) char ldsraw[128 * 264 * 2];
  float* lA = (float*)ldsraw;                 // [8 slots][128 rows][4 f32]
  u16* lB = (u16*)(ldsraw + 16384);           // [4 kgslots][256 cols][8 bf16]
  u16* lT = (u16*)ldsraw;                     // [128 rows][264 cols]

  const int t = threadIdx.x;
  const int lane = t & 63;
  const int w = t >> 6;
  const int l31 = lane & 31, lhi = lane >> 5;
  const int rb = w >> 1, cg = w & 1;
  const int tile_m = blockIdx.x >> 1;
  const int row0 = tile_m * 128;
  const int col0 = (blockIdx.x & 1) * 256;

  f32x16 acc[4];
#pragma unroll
  for (int ct = 0; ct < 4; ++ct)
#pragma unroll
    for (int r = 0; r < 16; ++r) acc[ct][r] = 0.f;

  const int arow = rb * 32 + l31;

#pragma unroll 1
  for (int kt = 0; kt < 16; ++kt) {
    const int k0 = kt * 32;
#pragma unroll
    for (int s = 0; s < 2; ++s) {
      int G = s * 512 + w * 64 + lane;
      int slot = G >> 7, row = G & 127;
      gload_lds16(x + (size_t)(row0 + row) * 512 + k0 + slot * 4,
                  (char*)lA + (size_t)(s * 512 + w * 64) * 16);
    }
#pragma unroll
    for (int s = 0; s < 2; ++s) {
      int G = s * 512 + w * 64 + lane;
      int kg = G >> 8, col = G & 255;
      gload_lds16(wbt + (size_t)(col0 + col) * 512 + k0 + kg * 8,
                  (char*)lB + (size_t)(s * 512 + w * 64) * 16);
    }
    __syncthreads();
#pragma unroll
    for (int ks = 0; ks < 2; ++ks) {
      const int slot = ks * 4 + lhi * 2;
      f32x4 fa0 = *reinterpret_cast<const f32x4*>(&lA[(slot * 128 + arow) * 4]);
      f32x4 fa1 = *reinterpret_cast<const f32x4*>(&lA[((slot + 1) * 128 + arow) * 4]);
      bf16x8 af;
#pragma unroll
      for (int j = 0; j < 4; ++j) {
        af[j] = (__bf16)fa0[j];
        af[j + 4] = (__bf16)fa1[j];
      }
#pragma unroll
      for (int ct = 0; ct < 4; ++ct) {
        const int colv = cg * 128 + ct * 32 + l31;
        bf16x8 bv = *reinterpret_cast<const bf16x8*>(&lB[((ks * 2 + lhi) * 256 + colv) * 8]);
        acc[ct] = __builtin_amdgcn_mfma_f32_32x32x16_bf16(af, bv, acc[ct], 0, 0, 0);
      }
    }
    __syncthreads();
  }

  // epilogue: C frags -> lT (bf16), then coalesced writes of hbf and hbt
#pragma unroll
  for (int ct = 0; ct < 4; ++ct) {
    const int colv = cg * 128 + ct * 32 + l31;
#pragma unroll
    for (int r = 0; r < 16; ++r) {
      int row = rb * 32 + (r & 3) + 8 * (r >> 2) + 4 * lhi;
      lT[row * 264 + colv] = f2bf(acc[ct][r]);
    }
  }
  __syncthreads();
#pragma unroll
  for (int rsub = 0; rsub < 8; ++rsub) {
    int G = rsub * 512 + t;
    int row = G >> 5, g = G & 31;
    uint4 v = *reinterpret_cast<const uint4*>(&lT[row * 264 + g * 8]);
    *reinterpret_cast<uint4*>(&hbf[(size_t)(row0 + row) * 512 + col0 + g * 8]) = v;
  }
  const int bb = row0 >> 10;
  const int nb = row0 & 1023;
#pragma unroll
  for (int rsub = 0; rsub < 8; ++rsub) {
    int G = rsub * 512 + t;
    int col = G & 255;
    int rc = ((rsub * 2) + (t >> 8)) & 15;
    u32 wd[4];
#pragma unroll
    for (int jj = 0; jj < 4; ++jj) {
      u16 lo = lT[(rc * 8 + 2 * jj) * 264 + col];
      u16 hi = lT[(rc * 8 + 2 * jj + 1) * 264 + col];
      wd[jj] = (u32)lo | ((u32)hi << 16);
    }
    uint4 o = {wd[0], wd[1], wd[2], wd[3]};
    *reinterpret_cast<uint4*>(&hbt[(size_t)(bb * 512 + col0 + col) * 1024 + nb + rc * 8]) = o;
  }
}

// ---------- score: s1L[row]=h.a1*log2e, s2L[row]=h.a2*log2e ----------
__global__ __launch_bounds__(256) void k_score(const u16* __restrict__ hbf, const float* __restrict__ a,
                                               float* __restrict__ s1L, float* __restrict__ s2L) {
  const int lane = threadIdx.x & 63;
  const int w = threadIdx.x >> 6;
  const int row = blockIdx.x * 4 + w;
  const u16* hp = hbf + (size_t)row * 512 + lane * 8;
  uint4 hv = *reinterpret_cast<const uint4*>(hp);
  const float* a1 = a + lane * 8;
  const float* a2 = a + 512 + lane * 8;
  u32 words[4] = {hv.x, hv.y, hv.z, hv.w};
  float d1 = 0.f, d2 = 0.f;
#pragma unroll
  for (int j = 0; j < 8; ++j) {
    float h = bf2f((u16)(words[j >> 1] >> ((j & 1) * 16)));
    d1 += h * a1[j];
    d2 += h * a2[j];
  }
#pragma unroll
  for (int off = 32; off > 0; off >>= 1) {
    d1 += __shfl_down(d1, off);
    d2 += __shfl_down(d2, off);
  }
  if (lane == 0) { s1L[row] = d1 * LOG2E; s2L[row] = d2 * LOG2E; }
}

// ---------- denom: inv[row] = 1 / sum_m exp2(lrelu-scaled e) ----------
__global__ __launch_bounds__(256) void k_denom(const float* __restrict__ s1Lg, const float* __restrict__ s2Lg,
                                               float* __restrict__ invg) {
  const int lane = threadIdx.x & 63;
  const int w = threadIdx.x >> 6;
  const int row = blockIdx.x * 4 + w;
  const int b = row >> 10;
  const float s1v = s1Lg[row];
  const float* s2p = s2Lg + ((size_t)b << 10);
  float sum = 0.f;
#pragma unroll
  for (int i = 0; i < 16; ++i) {
    float e = s1v + s2p[i * 64 + lane];
    sum += exp2f(fmaxf(e, ALPHA * e));
  }
#pragma unroll
  for (int off = 32; off > 0; off >>= 1) sum += __shfl_xor(sum, off);
  if (lane == 0) invg[row] = 1.0f / sum;
}

// ---------- attn: LDS-staged PV GEMM, double-buffered, swizzled B-reads ----------
__global__ __launch_bounds__(512, 2) void k_attn(const u16* __restrict__ hbt, const u16* __restrict__ hbf,
                                                 const float* __restrict__ s1Lg, const float* __restrict__ s2Lg,
                                                 const float* __restrict__ invg, const float* __restrict__ betag,
                                                 float* __restrict__ out) {
  __shared__ __attribute__((aligned(16))) u16 bbuf[2][256 * 64];   // [col][m-granule, XOR-swizzled]
  __shared__ __attribute__((aligned(16))) float e1_l[1024];
  __shared__ __attribute__((aligned(16))) float e2_l[1024];
  const int t = threadIdx.x;
  const int lane = t & 63;
  const int w = t >> 6;
  const int l31 = lane & 31, lhi = lane >> 5;

  // XCD swizzle: all 16 blocks of a batch on one XCD (2 batches/XCD L2)
  const int B = blockIdx.x;
  const int b = (B & 7) * 2 + ((B >> 3) & 1);
  const int j = B >> 4;
  const int n0 = (j >> 1) * 128;
  const int c0 = (j & 1) * 256;

  const u16* hb = hbt + (size_t)b * 512 * 1024;

  for (int i = t; i < 1024; i += 512) {
    float v = s2Lg[b * 1024 + i];
    e1_l[i] = exp2f(v);
    e2_l[i] = exp2f(ALPHA * v);
  }

  // stage chunk 0: 2048 granules of 16B; per-thread 4; source granule XOR-pre-swizzled
#pragma unroll
  for (int i = 0; i < 4; ++i) {
    int G = i * 512 + t;
    int c = G >> 3, g = G & 7;
    int gs = g ^ (c & 7);
    gload_lds16(hb + (size_t)(c0 + c) * 1024 + gs * 8,
                (char*)bbuf[0] + (size_t)(i * 512 + w * 64) * 16);
  }

  const int rb = w >> 1, cg = w & 1;
  const int myrow = n0 + rb * 32 + l31;
  const float s1v = s1Lg[b * 1024 + myrow];
  const float c1 = exp2f(s1v), c2 = exp2f(ALPHA * s1v);
  const float thr = exp2f(-s1v);      // e>0  <=>  exp2(s2) > exp2(-s1)

  f32x16 acc[4];
#pragma unroll
  for (int ct = 0; ct < 4; ++ct)
#pragma unroll
    for (int r = 0; r < 16; ++r) acc[ct][r] = 0.f;

  __syncthreads();   // tables + chunk-0 staging complete (implicit vmcnt drain)

#pragma unroll 1
  for (int mt = 0; mt < 16; ++mt) {
    const int cur = mt & 1;
    if (mt < 15) {   // issue next chunk's loads before compute (overlap)
#pragma unroll
      for (int i = 0; i < 4; ++i) {
        int G = i * 512 + t;
        int c = G >> 3, g = G & 7;
        int gs = g ^ (c & 7);
        gload_lds16(hb + (size_t)(c0 + c) * 1024 + (mt + 1) * 64 + gs * 8,
                    (char*)bbuf[cur ^ 1] + (size_t)(i * 512 + w * 64) * 16);
      }
    }
#pragma unroll
    for (int step = 0; step < 4; ++step) {
      const int mo = mt * 64 + step * 16 + lhi * 8;
      f32x4 ea = *reinterpret_cast<const f32x4*>(&e1_l[mo]);
      f32x4 eb = *reinterpret_cast<const f32x4*>(&e1_l[mo + 4]);
      f32x4 fa = *reinterpret_cast<const f32x4*>(&e2_l[mo]);
      f32x4 fb = *reinterpret_cast<const f32x4*>(&e2_l[mo + 4]);
      bf16x8 af;
#pragma unroll
      for (int q = 0; q < 4; ++q) {
        float p0 = (ea[q] > thr) ? c1 * ea[q] : c2 * fa[q];
        float p1 = (eb[q] > thr) ? c1 * eb[q] : c2 * fb[q];
        af[q] = (__bf16)p0;
        af[q + 4] = (__bf16)p1;
      }
      const int gm = step * 2 + lhi;
#pragma unroll
      for (int ct = 0; ct < 4; ++ct) {
        const int c = cg * 128 + ct * 32 + l31;
        bf16x8 bv = *reinterpret_cast<const bf16x8*>(&bbuf[cur][c * 64 + ((gm ^ (c & 7)) * 8)]);
        acc[ct] = __builtin_amdgcn_mfma_f32_32x32x16_bf16(af, bv, acc[ct], 0, 0, 0);
      }
    }
    __syncthreads();   // drains vmcnt (next chunk staged) + LDS reads done
  }

  const float beta = betag[0];
  const float* invb = invg + b * 1024;
  const u16* hf = hbf + (size_t)b * 1024 * 512;
#pragma unroll
  for (int ct = 0; ct < 4; ++ct) {
    const int colv = c0 + cg * 128 + ct * 32 + l31;
#pragma unroll
    for (int rg = 0; rg < 4; ++rg) {
      const int rowb = n0 + rb * 32 + rg * 8 + lhi * 4;
      f32x4 iv = *reinterpret_cast<const f32x4*>(&invb[rowb]);
#pragma unroll
      for (int q = 0; q < 4; ++q) {
        float hv = bf2f(hf[(size_t)(rowb + q) * 512 + colv]);
        float xv = acc[ct][rg * 4 + q] * iv[q] + beta * hv;
        out[((size_t)b * 1024 + rowb + q) * 512 + colv] = xv > 0.f ? xv : __expf(xv) - 1.0f;
      }
    }
  }
}

extern "C" void kernel_launch(void* const* d_in, const int* in_sizes, int n_in,
                              void* d_out, int out_size, void* d_ws, size_t ws_size,
                              hipStream_t stream) {
  const float* x = (const float*)d_in[0];
  const float* W = (const float*)d_in[1];
  const float* a = (const float*)d_in[2];
  const float* beta = (const float*)d_in[3];
  float* out = (float*)d_out;

  char* ws = (char*)d_ws;
  u16* hbf = (u16*)ws;
  u16* hbt = (u16*)(ws + (16u << 20));
  u16* wbt = (u16*)(ws + (32u << 20));
  float* s1L = (float*)(ws + (32u << 20) + (512u << 10));
  float* s2L = (float*)(ws + (32u << 20) + (576u << 10));
  float* inv = (float*)(ws + (32u << 20) + (640u << 10));

  k_cast_wT<<<1024, 256, 0, stream>>>(W, wbt);
  k_gemm1<<<256, 512, 0, stream>>>(x, wbt, hbf, hbt);
  k_score<<<4096, 256, 0, stream>>>(hbf, a, s1L, s2L);
  k_denom<<<4096, 256, 0, stream>>>(s1L, s2L, inv);
  k_attn<<<256, 512, 0, stream>>>(hbt, hbf, s1L, s2L, inv, beta, out);
}

// Round 5
// 86.131 us; speedup vs baseline: 2.1255x; 1.1398x over previous
//
#include <hip/hip_runtime.h>

using u16 = unsigned short;
using u32 = unsigned int;

#define ALPHA 0.2f
#define LOG2E 1.4426950408889634f

typedef __bf16 bf16x8 __attribute__((ext_vector_type(8)));
typedef float f32x4 __attribute__((ext_vector_type(4)));
typedef float f32x16 __attribute__((ext_vector_type(16)));

__device__ __forceinline__ u16 f2bf(float f) {
  u32 u = __builtin_bit_cast(u32, f);
  u += 0x7FFFu + ((u >> 16) & 1u);   // RTNE
  return (u16)(u >> 16);
}
__device__ __forceinline__ float bf2f(u16 h) {
  u32 u = ((u32)h) << 16;
  return __builtin_bit_cast(float, u);
}
__device__ __forceinline__ void gload_lds16(const void* g, void* l) {
  __builtin_amdgcn_global_load_lds((__attribute__((address_space(1))) void*)g,
                                   (__attribute__((address_space(3))) void*)l,
                                   16, 0, 0);
}

// ---------- cast+transpose W: wbt[n][k] = bf16(W[k][n]) ----------
__global__ __launch_bounds__(256) void k_cast_wT(const float* __restrict__ W, u16* __restrict__ wbt) {
  int idx = blockIdx.x * 256 + threadIdx.x;
  int k = idx >> 9, n = idx & 511;
  wbt[n * 512 + k] = f2bf(W[idx]);
}

// ---------- gemm1: h = x@W (M=16384,K=512,N=512). 128x128 tile, 4 waves.
// XOR-swizzled LDS staging, double-buffered. Epilogue: lT -> hbf + hbt + score partials.
__global__ __launch_bounds__(256, 3) void k_gemm1(const float* __restrict__ x, const u16* __restrict__ wbt,
                                                  const float* __restrict__ a,
                                                  u16* __restrict__ hbf, u16* __restrict__ hbt,
                                                  float* __restrict__ s1p, float* __restrict__ s2p) {
  __shared__ __attribute__((aligned(16))) char lds[49152];
  __shared__ __attribute__((aligned(16))) float a_l[256];

  const int t = threadIdx.x;
  const int lane = t & 63;
  const int w = t >> 6;
  const int l31 = lane & 31, lhi = lane >> 5;
  const int rb = w >> 1, cg = w & 1;
  const int tile_m = blockIdx.x >> 2;
  const int cb = blockIdx.x & 3;
  const int row0 = tile_m * 128;
  const int col0 = cb * 128;

  a_l[t] = (t < 128) ? a[col0 + t] : a[512 + col0 + (t - 128)];

  f32x16 acc[2][2];
#pragma unroll
  for (int i = 0; i < 2; ++i)
#pragma unroll
    for (int j = 0; j < 2; ++j)
#pragma unroll
      for (int r = 0; r < 16; ++r) acc[i][j][r] = 0.f;

#define STAGE_CHUNK(kt, buf)                                                              \
  {                                                                                       \
    const int k0_ = (kt) * 32;                                                            \
    _Pragma("unroll")                                                                     \
    for (int i = 0; i < 4; ++i) {                                                         \
      int G = i * 256 + t;                                                                \
      int row = G >> 3, ks = G & 7;                                                       \
      gload_lds16(x + (size_t)(row0 + row) * 512 + k0_ + ((ks ^ (row & 7)) * 4),          \
                  lds + (buf) * 16384 + (size_t)(i * 256 + w * 64) * 16);                 \
    }                                                                                     \
    _Pragma("unroll")                                                                     \
    for (int i = 0; i < 2; ++i) {                                                         \
      int G = i * 256 + t;                                                                \
      int col = G >> 2, ks = G & 3;                                                       \
      gload_lds16(wbt + (size_t)(col0 + col) * 512 + k0_ + ((ks ^ ((col >> 1) & 3)) * 8), \
                  lds + 32768 + (buf) * 8192 + (size_t)(i * 256 + w * 64) * 16);          \
    }                                                                                     \
  }

  STAGE_CHUNK(0, 0);
  __syncthreads();

#pragma unroll 1
  for (int kt = 0; kt < 16; ++kt) {
    const int cur = kt & 1;
    if (kt < 15) STAGE_CHUNK(kt + 1, cur ^ 1);
    const char* Ab = lds + cur * 16384;
    const char* Bb = lds + 32768 + cur * 8192;
#pragma unroll
    for (int ks = 0; ks < 2; ++ks) {
      bf16x8 af[2];
#pragma unroll
      for (int sub = 0; sub < 2; ++sub) {
        const int arow = rb * 64 + sub * 32 + l31;
        const int kg = ks * 4 + lhi * 2;
        f32x4 fa0 = *reinterpret_cast<const f32x4*>(Ab + (size_t)(arow * 8 + (kg ^ (arow & 7))) * 16);
        f32x4 fa1 = *reinterpret_cast<const f32x4*>(Ab + (size_t)(arow * 8 + ((kg + 1) ^ (arow & 7))) * 16);
#pragma unroll
        for (int j = 0; j < 4; ++j) {
          af[sub][j] = (__bf16)fa0[j];
          af[sub][j + 4] = (__bf16)fa1[j];
        }
      }
      bf16x8 bfr[2];
#pragma unroll
      for (int bt = 0; bt < 2; ++bt) {
        const int bcol = cg * 64 + bt * 32 + l31;
        const int kslot = (ks * 2 + lhi) ^ ((bcol >> 1) & 3);
        bfr[bt] = *reinterpret_cast<const bf16x8*>(Bb + (size_t)(bcol * 4 + kslot) * 16);
      }
#pragma unroll
      for (int sub = 0; sub < 2; ++sub)
#pragma unroll
        for (int bt = 0; bt < 2; ++bt)
          acc[sub][bt] = __builtin_amdgcn_mfma_f32_32x32x16_bf16(af[sub], bfr[bt], acc[sub][bt], 0, 0, 0);
    }
    __syncthreads();
  }
#undef STAGE_CHUNK

  // epilogue: frags -> lT [128][136] u16
  u16* lT = (u16*)lds;
#pragma unroll
  for (int sub = 0; sub < 2; ++sub)
#pragma unroll
    for (int bt = 0; bt < 2; ++bt) {
      const int col = cg * 64 + bt * 32 + l31;
#pragma unroll
      for (int r = 0; r < 16; ++r) {
        int row = rb * 64 + sub * 32 + (r & 3) + 8 * (r >> 2) + 4 * lhi;
        lT[row * 136 + col] = f2bf(acc[sub][bt][r]);
      }
    }
  __syncthreads();

  // hbf writes: [row][col] coalesced — 128 rows x 16 granules = 2048 granules (8 rounds)
#pragma unroll
  for (int i = 0; i < 8; ++i) {
    int G = i * 256 + t;
    int row = G >> 4, g = G & 15;
    uint4 v = *reinterpret_cast<const uint4*>(&lT[row * 136 + g * 8]);
    *reinterpret_cast<uint4*>(&hbf[(size_t)(row0 + row) * 512 + col0 + g * 8]) = v;
  }
  // hbt writes: [b][f][m]
  const int bb = row0 >> 10;
  const int nb = row0 & 1023;
#pragma unroll
  for (int i = 0; i < 8; ++i) {
    int G = i * 256 + t;
    int col = G & 127, rg = G >> 7;
    u32 wd[4];
#pragma unroll
    for (int jj = 0; jj < 4; ++jj) {
      u16 lo = lT[(rg * 8 + 2 * jj) * 136 + col];
      u16 hi = lT[(rg * 8 + 2 * jj + 1) * 136 + col];
      wd[jj] = (u32)lo | ((u32)hi << 16);
    }
    uint4 o = {wd[0], wd[1], wd[2], wd[3]};
    *reinterpret_cast<uint4*>(&hbt[(size_t)(bb * 512 + col0 + col) * 1024 + nb + rg * 8]) = o;
  }
  // score partials
  {
    const int r2 = t >> 1, half = t & 1;
    float d1 = 0.f, d2 = 0.f;
#pragma unroll
    for (int i = 0; i < 8; ++i) {
      uint4 v = *reinterpret_cast<const uint4*>(&lT[r2 * 136 + half * 64 + i * 8]);
      u32 wds[4] = {v.x, v.y, v.z, v.w};
#pragma unroll
      for (int j = 0; j < 8; ++j) {
        float h = bf2f((u16)(wds[j >> 1] >> ((j & 1) * 16)));
        d1 += h * a_l[half * 64 + i * 8 + j];
        d2 += h * a_l[128 + half * 64 + i * 8 + j];
      }
    }
    d1 += __shfl_xor(d1, 1);
    d2 += __shfl_xor(d2, 1);
    if (half == 0) {
      s1p[cb * 16384 + row0 + r2] = d1;
      s2p[cb * 16384 + row0 + r2] = d2;
    }
  }
}

// ---------- reduce score partials -> s1L, s2L (scaled by log2e) ----------
__global__ __launch_bounds__(256) void k_reduce(const float* __restrict__ s1p, const float* __restrict__ s2p,
                                                float* __restrict__ s1L, float* __restrict__ s2L) {
  int id = blockIdx.x * 256 + threadIdx.x;
  float d1 = s1p[id] + s1p[16384 + id] + s1p[32768 + id] + s1p[49152 + id];
  float d2 = s2p[id] + s2p[16384 + id] + s2p[32768 + id] + s2p[49152 + id];
  s1L[id] = d1 * LOG2E;
  s2L[id] = d2 * LOG2E;
}

// ---------- denom: inv[row] = 1 / sum_m exp2(lrelu(e)) ----------
__global__ __launch_bounds__(256) void k_denom(const float* __restrict__ s1Lg, const float* __restrict__ s2Lg,
                                               float* __restrict__ invg) {
  const int lane = threadIdx.x & 63;
  const int w = threadIdx.x >> 6;
  const int row = blockIdx.x * 4 + w;
  const int b = row >> 10;
  const float s1v = s1Lg[row];
  const float* s2p = s2Lg + ((size_t)b << 10);
  float sum = 0.f;
#pragma unroll
  for (int i = 0; i < 16; ++i) {
    float e = s1v + s2p[i * 64 + lane];
    sum += exp2f(fmaxf(e, ALPHA * e));
  }
#pragma unroll
  for (int off = 32; off > 0; off >>= 1) sum += __shfl_xor(sum, off);
  if (lane == 0) invg[row] = 1.0f / sum;
}

// ---------- attn: PV GEMM, 128x128 tile, 4 waves, dbuf LDS staging ----------
__global__ __launch_bounds__(256, 3) void k_attn(const u16* __restrict__ hbt, const u16* __restrict__ hbf,
                                                 const float* __restrict__ s1Lg, const float* __restrict__ s2Lg,
                                                 const float* __restrict__ invg, const float* __restrict__ betag,
                                                 float* __restrict__ out) {
  __shared__ __attribute__((aligned(16))) u16 bbuf[2][128 * 64];
  __shared__ __attribute__((aligned(16))) float e1_l[1024];
  __shared__ __attribute__((aligned(16))) float e2_l[1024];
  const int t = threadIdx.x;
  const int lane = t & 63;
  const int w = t >> 6;
  const int l31 = lane & 31, lhi = lane >> 5;

  const int B = blockIdx.x;
  const int b = (B & 7) * 2 + ((B >> 3) & 1);
  const int j = B >> 4;                 // 0..31
  const int n0 = (j >> 2) * 128;
  const int c0 = (j & 3) * 128;

  const u16* hb = hbt + (size_t)b * 512 * 1024;

  for (int i = t; i < 1024; i += 256) {
    float v = s2Lg[b * 1024 + i];
    e1_l[i] = exp2f(v);
    e2_l[i] = exp2f(ALPHA * v);
  }

#define STAGE_ATTN(mt, buf)                                                       \
  {                                                                               \
    _Pragma("unroll")                                                             \
    for (int i = 0; i < 4; ++i) {                                                 \
      int G = i * 256 + t;                                                        \
      int c = G >> 3, g = G & 7;                                                  \
      gload_lds16(hb + (size_t)(c0 + c) * 1024 + (mt) * 64 + ((g ^ (c & 7)) * 8), \
                  (char*)bbuf[buf] + (size_t)(i * 256 + w * 64) * 16);            \
    }                                                                             \
  }

  STAGE_ATTN(0, 0);

  const int myrow = n0 + w * 32 + l31;
  const float s1v = s1Lg[b * 1024 + myrow];
  const float c1 = exp2f(s1v), c2 = exp2f(ALPHA * s1v);
  const float thr = exp2f(-s1v);        // e>0 <=> exp2(s2L) > exp2(-s1L)

  f32x16 acc[4];
#pragma unroll
  for (int ct = 0; ct < 4; ++ct)
#pragma unroll
    for (int r = 0; r < 16; ++r) acc[ct][r] = 0.f;

  __syncthreads();   // tables + chunk 0 staged

#pragma unroll 1
  for (int mt = 0; mt < 16; ++mt) {
    const int cur = mt & 1;
    if (mt < 15) STAGE_ATTN(mt + 1, cur ^ 1);
#pragma unroll
    for (int step = 0; step < 4; ++step) {
      const int mo = mt * 64 + step * 16 + lhi * 8;
      f32x4 ea = *reinterpret_cast<const f32x4*>(&e1_l[mo]);
      f32x4 eb = *reinterpret_cast<const f32x4*>(&e1_l[mo + 4]);
      f32x4 fa = *reinterpret_cast<const f32x4*>(&e2_l[mo]);
      f32x4 fb = *reinterpret_cast<const f32x4*>(&e2_l[mo + 4]);
      bf16x8 af;
#pragma unroll
      for (int q = 0; q < 4; ++q) {
        float p0 = (ea[q] > thr) ? c1 * ea[q] : c2 * fa[q];
        float p1 = (eb[q] > thr) ? c1 * eb[q] : c2 * fb[q];
        af[q] = (__bf16)p0;
        af[q + 4] = (__bf16)p1;
      }
      const int gm = step * 2 + lhi;
#pragma unroll
      for (int ct = 0; ct < 4; ++ct) {
        const int c = ct * 32 + l31;
        bf16x8 bv = *reinterpret_cast<const bf16x8*>(&bbuf[cur][c * 64 + ((gm ^ (c & 7)) * 8)]);
        acc[ct] = __builtin_amdgcn_mfma_f32_32x32x16_bf16(af, bv, acc[ct], 0, 0, 0);
      }
    }
    __syncthreads();
  }
#undef STAGE_ATTN

  const float beta = betag[0];
  const float* invb = invg + b * 1024;
  const u16* hf = hbf + (size_t)b * 1024 * 512;
#pragma unroll
  for (int ct = 0; ct < 4; ++ct) {
    const int colv = c0 + ct * 32 + l31;
#pragma unroll
    for (int rg = 0; rg < 4; ++rg) {
      const int rowb = n0 + w * 32 + rg * 8 + lhi * 4;
      f32x4 iv = *reinterpret_cast<const f32x4*>(&invb[rowb]);
#pragma unroll
      for (int q = 0; q < 4; ++q) {
        float hv = bf2f(hf[(size_t)(rowb + q) * 512 + colv]);
        float xv = acc[ct][rg * 4 + q] * iv[q] + beta * hv;
        out[((size_t)b * 1024 + rowb + q) * 512 + colv] = xv > 0.f ? xv : __expf(xv) - 1.0f;
      }
    }
  }
}

extern "C" void kernel_launch(void* const* d_in, const int* in_sizes, int n_in,
                              void* d_out, int out_size, void* d_ws, size_t ws_size,
                              hipStream_t stream) {
  const float* x = (const float*)d_in[0];
  const float* W = (const float*)d_in[1];
  const float* a = (const float*)d_in[2];
  const float* beta = (const float*)d_in[3];
  float* out = (float*)d_out;

  char* ws = (char*)d_ws;
  u16* hbf = (u16*)ws;                              // 16 MB
  u16* hbt = (u16*)(ws + (16u << 20));              // 16 MB
  u16* wbt = (u16*)(ws + (32u << 20));              // 512 KB
  float* s1p = (float*)(ws + (32u << 20) + (512u << 10));   // 256 KB
  float* s2p = (float*)(ws + (32u << 20) + (768u << 10));   // 256 KB
  float* s1L = (float*)(ws + (33u << 20));          // 64 KB
  float* s2L = (float*)(ws + (33u << 20) + (64u << 10));
  float* inv = (float*)(ws + (33u << 20) + (128u << 10));

  k_cast_wT<<<1024, 256, 0, stream>>>(W, wbt);
  k_gemm1<<<512, 256, 0, stream>>>(x, wbt, a, hbf, hbt, s1p, s2p);
  k_reduce<<<64, 256, 0, stream>>>(s1p, s2p, s1L, s2L);
  k_denom<<<4096, 256, 0, stream>>>(s1L, s2L, inv);
  k_attn<<<512, 256, 0, stream>>>(hbt, hbf, s1L, s2L, inv, beta, out);
}

// Round 6
// 74.590 us; speedup vs baseline: 2.4544x; 1.1547x over previous
//
#include <hip/hip_runtime.h>

using u16 = unsigned short;
using u32 = unsigned int;

#define ALPHA 0.2f
#define LOG2E 1.4426950408889634f

typedef __bf16 bf16x8 __attribute__((ext_vector_type(8)));
typedef float f32x4 __attribute__((ext_vector_type(4)));
typedef float f32x16 __attribute__((ext_vector_type(16)));

__device__ __forceinline__ u16 f2bf(float f) {
  u32 u = __builtin_bit_cast(u32, f);
  u += 0x7FFFu + ((u >> 16) & 1u);   // RTNE
  return (u16)(u >> 16);
}
__device__ __forceinline__ float bf2f(u16 h) {
  u32 u = ((u32)h) << 16;
  return __builtin_bit_cast(float, u);
}
__device__ __forceinline__ void gload_lds16(const void* g, void* l) {
  __builtin_amdgcn_global_load_lds((__attribute__((address_space(1))) void*)g,
                                   (__attribute__((address_space(3))) void*)l,
                                   16, 0, 0);
}

// ---------- cast+transpose W: wbt[n][k] = bf16(W[k][n]) ----------
__global__ __launch_bounds__(256) void k_cast_wT(const float* __restrict__ W, u16* __restrict__ wbt) {
  int idx = blockIdx.x * 256 + threadIdx.x;
  int k = idx >> 9, n = idx & 511;
  wbt[n * 512 + k] = f2bf(W[idx]);
}

// ---------- gemm1: h = x@W (M=16384,K=512,N=512). 128x128 tile, 4 waves.
// Triple-buffered staging, counted vmcnt (never 0 in loop), raw s_barrier.
// Epilogue: lT -> hbf + hbt + score partials.
__global__ __launch_bounds__(256, 2) void k_gemm1(const float* __restrict__ x, const u16* __restrict__ wbt,
                                                  const float* __restrict__ a,
                                                  u16* __restrict__ hbf, u16* __restrict__ hbt,
                                                  float* __restrict__ s1p, float* __restrict__ s2p) {
  // [0,48K): 3x A buf (16KB f32 each); [48K,72K): 3x B buf (8KB bf16 each); lT aliases [0,34K)
  __shared__ __attribute__((aligned(16))) char lds[73728];
  __shared__ __attribute__((aligned(16))) float a_l[256];

  const int t = threadIdx.x;
  const int lane = t & 63;
  const int w = t >> 6;
  const int l31 = lane & 31, lhi = lane >> 5;
  const int rb = w >> 1, cg = w & 1;
  const int tile_m = blockIdx.x >> 2;
  const int cb = blockIdx.x & 3;
  const int row0 = tile_m * 128;
  const int col0 = cb * 128;

  a_l[t] = (t < 128) ? a[col0 + t] : a[512 + col0 + (t - 128)];

  f32x16 acc[2][2];
#pragma unroll
  for (int i = 0; i < 2; ++i)
#pragma unroll
    for (int j = 0; j < 2; ++j)
#pragma unroll
      for (int r = 0; r < 16; ++r) acc[i][j][r] = 0.f;

#define STAGE_G1(kt, Ab, Bb)                                                              \
  {                                                                                       \
    const int k0_ = (kt) * 32;                                                            \
    _Pragma("unroll")                                                                     \
    for (int i = 0; i < 4; ++i) {                                                         \
      int G = i * 256 + t;                                                                \
      int row = G >> 3, ks = G & 7;                                                       \
      gload_lds16(x + (size_t)(row0 + row) * 512 + k0_ + ((ks ^ (row & 7)) * 4),          \
                  (Ab) + (size_t)(i * 256 + w * 64) * 16);                                \
    }                                                                                     \
    _Pragma("unroll")                                                                     \
    for (int i = 0; i < 2; ++i) {                                                         \
      int G = i * 256 + t;                                                                \
      int col = G >> 2, ks = G & 3;                                                       \
      gload_lds16(wbt + (size_t)(col0 + col) * 512 + k0_ + ((ks ^ ((col >> 1) & 3)) * 8), \
                  (Bb) + (size_t)(i * 256 + w * 64) * 16);                                \
    }                                                                                     \
  }

#define COMPUTE_G1(Ab, Bb)                                                                         \
  {                                                                                                \
    _Pragma("unroll")                                                                              \
    for (int ks = 0; ks < 2; ++ks) {                                                               \
      bf16x8 af[2];                                                                                \
      _Pragma("unroll")                                                                            \
      for (int sub = 0; sub < 2; ++sub) {                                                          \
        const int arow = rb * 64 + sub * 32 + l31;                                                 \
        const int kg = ks * 4 + lhi * 2;                                                           \
        f32x4 fa0 = *reinterpret_cast<const f32x4*>((Ab) + (size_t)(arow * 8 + (kg ^ (arow & 7))) * 16); \
        f32x4 fa1 = *reinterpret_cast<const f32x4*>((Ab) + (size_t)(arow * 8 + ((kg + 1) ^ (arow & 7))) * 16); \
        _Pragma("unroll")                                                                          \
        for (int j = 0; j < 4; ++j) {                                                              \
          af[sub][j] = (__bf16)fa0[j];                                                             \
          af[sub][j + 4] = (__bf16)fa1[j];                                                         \
        }                                                                                          \
      }                                                                                            \
      bf16x8 bfr[2];                                                                               \
      _Pragma("unroll")                                                                            \
      for (int bt = 0; bt < 2; ++bt) {                                                             \
        const int bcol = cg * 64 + bt * 32 + l31;                                                  \
        const int kslot = (ks * 2 + lhi) ^ ((bcol >> 1) & 3);                                      \
        bfr[bt] = *reinterpret_cast<const bf16x8*>((Bb) + (size_t)(bcol * 4 + kslot) * 16);        \
      }                                                                                            \
      _Pragma("unroll")                                                                            \
      for (int sub = 0; sub < 2; ++sub)                                                            \
        _Pragma("unroll")                                                                          \
        for (int bt = 0; bt < 2; ++bt)                                                             \
          acc[sub][bt] = __builtin_amdgcn_mfma_f32_32x32x16_bf16(af[sub], bfr[bt], acc[sub][bt], 0, 0, 0); \
    }                                                                                              \
  }

  char* Ac = lds;             char* Bc = lds + 49152;
  char* An = lds + 16384;     char* Bn = lds + 57344;
  char* As = lds + 32768;     char* Bs = lds + 65536;

  STAGE_G1(0, Ac, Bc);
  STAGE_G1(1, An, Bn);
  __builtin_amdgcn_sched_barrier(0);
  asm volatile("s_waitcnt vmcnt(6) lgkmcnt(0)" ::: "memory");   // chunk 0 landed; a_l visible
  __builtin_amdgcn_s_barrier();
  __builtin_amdgcn_sched_barrier(0);

#pragma unroll 1
  for (int kt = 0; kt < 14; ++kt) {
    STAGE_G1(kt + 2, As, Bs);
    COMPUTE_G1(Ac, Bc);
    __builtin_amdgcn_sched_barrier(0);
    asm volatile("s_waitcnt vmcnt(6)" ::: "memory");            // chunk kt+1 landed; kt+2 in flight
    __builtin_amdgcn_s_barrier();
    __builtin_amdgcn_sched_barrier(0);
    char* ta = Ac; Ac = An; An = As; As = ta;
    char* tb = Bc; Bc = Bn; Bn = Bs; Bs = tb;
  }
  COMPUTE_G1(Ac, Bc);                                           // chunk 14
  __builtin_amdgcn_sched_barrier(0);
  asm volatile("s_waitcnt vmcnt(0)" ::: "memory");              // chunk 15 landed
  __builtin_amdgcn_s_barrier();
  __builtin_amdgcn_sched_barrier(0);
  COMPUTE_G1(An, Bn);                                           // chunk 15
#undef STAGE_G1
#undef COMPUTE_G1

  __syncthreads();   // all LDS reads done before lT overwrites staging buffers

  // epilogue: frags -> lT [128][136] u16
  u16* lT = (u16*)lds;
#pragma unroll
  for (int sub = 0; sub < 2; ++sub)
#pragma unroll
    for (int bt = 0; bt < 2; ++bt) {
      const int col = cg * 64 + bt * 32 + l31;
#pragma unroll
      for (int r = 0; r < 16; ++r) {
        int row = rb * 64 + sub * 32 + (r & 3) + 8 * (r >> 2) + 4 * lhi;
        lT[row * 136 + col] = f2bf(acc[sub][bt][r]);
      }
    }
  __syncthreads();

  // hbf writes: 128 rows x 16 granules = 2048 granules (8 rounds)
#pragma unroll
  for (int i = 0; i < 8; ++i) {
    int G = i * 256 + t;
    int row = G >> 4, g = G & 15;
    uint4 v = *reinterpret_cast<const uint4*>(&lT[row * 136 + g * 8]);
    *reinterpret_cast<uint4*>(&hbf[(size_t)(row0 + row) * 512 + col0 + g * 8]) = v;
  }
  // hbt writes: [b][f][m]
  const int bb = row0 >> 10;
  const int nb = row0 & 1023;
#pragma unroll
  for (int i = 0; i < 8; ++i) {
    int G = i * 256 + t;
    int col = G & 127, rg = G >> 7;
    u32 wd[4];
#pragma unroll
    for (int jj = 0; jj < 4; ++jj) {
      u16 lo = lT[(rg * 8 + 2 * jj) * 136 + col];
      u16 hi = lT[(rg * 8 + 2 * jj + 1) * 136 + col];
      wd[jj] = (u32)lo | ((u32)hi << 16);
    }
    uint4 o = {wd[0], wd[1], wd[2], wd[3]};
    *reinterpret_cast<uint4*>(&hbt[(size_t)(bb * 512 + col0 + col) * 1024 + nb + rg * 8]) = o;
  }
  // score partials
  {
    const int r2 = t >> 1, half = t & 1;
    float d1 = 0.f, d2 = 0.f;
#pragma unroll
    for (int i = 0; i < 8; ++i) {
      uint4 v = *reinterpret_cast<const uint4*>(&lT[r2 * 136 + half * 64 + i * 8]);
      u32 wds[4] = {v.x, v.y, v.z, v.w};
#pragma unroll
      for (int j = 0; j < 8; ++j) {
        float h = bf2f((u16)(wds[j >> 1] >> ((j & 1) * 16)));
        d1 += h * a_l[half * 64 + i * 8 + j];
        d2 += h * a_l[128 + half * 64 + i * 8 + j];
      }
    }
    d1 += __shfl_xor(d1, 1);
    d2 += __shfl_xor(d2, 1);
    if (half == 0) {
      s1p[cb * 16384 + row0 + r2] = d1;
      s2p[cb * 16384 + row0 + r2] = d2;
    }
  }
}

// ---------- reduce score partials -> s1L, s2L (scaled by log2e) ----------
__global__ __launch_bounds__(256) void k_reduce(const float* __restrict__ s1p, const float* __restrict__ s2p,
                                                float* __restrict__ s1L, float* __restrict__ s2L) {
  int id = blockIdx.x * 256 + threadIdx.x;
  float d1 = s1p[id] + s1p[16384 + id] + s1p[32768 + id] + s1p[49152 + id];
  float d2 = s2p[id] + s2p[16384 + id] + s2p[32768 + id] + s2p[49152 + id];
  s1L[id] = d1 * LOG2E;
  s2L[id] = d2 * LOG2E;
}

// ---------- denom: inv[row] = 1 / sum_m exp2(lrelu(e)) ----------
__global__ __launch_bounds__(256) void k_denom(const float* __restrict__ s1Lg, const float* __restrict__ s2Lg,
                                               float* __restrict__ invg) {
  const int lane = threadIdx.x & 63;
  const int w = threadIdx.x >> 6;
  const int row = blockIdx.x * 4 + w;
  const int b = row >> 10;
  const float s1v = s1Lg[row];
  const float* s2p = s2Lg + ((size_t)b << 10);
  float sum = 0.f;
#pragma unroll
  for (int i = 0; i < 16; ++i) {
    float e = s1v + s2p[i * 64 + lane];
    sum += exp2f(fmaxf(e, ALPHA * e));
  }
#pragma unroll
  for (int off = 32; off > 0; off >>= 1) sum += __shfl_xor(sum, off);
  if (lane == 0) invg[row] = 1.0f / sum;
}

// ---------- attn: PV GEMM, 128x128 tile, 4 waves, triple-buffered counted-vmcnt ----------
__global__ __launch_bounds__(256, 2) void k_attn(const u16* __restrict__ hbt, const u16* __restrict__ hbf,
                                                 const float* __restrict__ s1Lg, const float* __restrict__ s2Lg,
                                                 const float* __restrict__ invg, const float* __restrict__ betag,
                                                 float* __restrict__ out) {
  __shared__ __attribute__((aligned(16))) u16 bbuf[3][8192];   // 3 x [128 cols][8 granules(8 m), swz]
  __shared__ __attribute__((aligned(16))) float e1_l[1024];
  __shared__ __attribute__((aligned(16))) float e2_l[1024];
  const int t = threadIdx.x;
  const int lane = t & 63;
  const int w = t >> 6;
  const int l31 = lane & 31, lhi = lane >> 5;

  const int B = blockIdx.x;
  const int b = (B & 7) * 2 + ((B >> 3) & 1);   // XCD swizzle: 2 batches/XCD L2
  const int j = B >> 4;                          // 0..31
  const int n0 = (j >> 2) * 128;
  const int c0 = (j & 3) * 128;

  const u16* hb = hbt + (size_t)b * 512 * 1024;

  // tables + per-row constants first (their internal waits precede staging issue)
  for (int i = t; i < 1024; i += 256) {
    float v = s2Lg[b * 1024 + i];
    e1_l[i] = exp2f(v);
    e2_l[i] = exp2f(ALPHA * v);
  }
  const int myrow = n0 + w * 32 + l31;
  const float s1v = s1Lg[b * 1024 + myrow];
  const float c1 = exp2f(s1v), c2 = exp2f(ALPHA * s1v);

#define STAGE_ATTN(mt, dst)                                                        \
  {                                                                                \
    _Pragma("unroll")                                                              \
    for (int i = 0; i < 4; ++i) {                                                  \
      int G = i * 256 + t;                                                         \
      int c = G >> 3, g = G & 7;                                                   \
      gload_lds16(hb + (size_t)(c0 + c) * 1024 + (mt) * 64 + ((g ^ (c & 7)) * 8),  \
                  (char*)(dst) + (size_t)(i * 256 + w * 64) * 16);                 \
    }                                                                              \
  }

#define COMPUTE_ATTN(mt, src)                                                                 \
  {                                                                                           \
    _Pragma("unroll")                                                                         \
    for (int step = 0; step < 4; ++step) {                                                    \
      const int mo = (mt) * 64 + step * 16 + lhi * 8;                                         \
      f32x4 ea = *reinterpret_cast<const f32x4*>(&e1_l[mo]);                                  \
      f32x4 eb = *reinterpret_cast<const f32x4*>(&e1_l[mo + 4]);                              \
      f32x4 fa = *reinterpret_cast<const f32x4*>(&e2_l[mo]);                                  \
      f32x4 fb = *reinterpret_cast<const f32x4*>(&e2_l[mo + 4]);                              \
      bf16x8 af;                                                                              \
      _Pragma("unroll")                                                                       \
      for (int q = 0; q < 4; ++q) {                                                           \
        af[q] = (__bf16)fmaxf(c1 * ea[q], c2 * fa[q]);                                        \
        af[q + 4] = (__bf16)fmaxf(c1 * eb[q], c2 * fb[q]);                                    \
      }                                                                                       \
      const int gm = step * 2 + lhi;                                                          \
      _Pragma("unroll")                                                                       \
      for (int ct = 0; ct < 4; ++ct) {                                                        \
        const int c = ct * 32 + l31;                                                          \
        bf16x8 bv = *reinterpret_cast<const bf16x8*>(&(src)[c * 64 + ((gm ^ (c & 7)) * 8)]);  \
        acc[ct] = __builtin_amdgcn_mfma_f32_32x32x16_bf16(af, bv, acc[ct], 0, 0, 0);          \
      }                                                                                       \
    }                                                                                         \
  }

  f32x16 acc[4];
#pragma unroll
  for (int ct = 0; ct < 4; ++ct)
#pragma unroll
    for (int r = 0; r < 16; ++r) acc[ct][r] = 0.f;

  u16* bcur = bbuf[0];
  u16* bnxt = bbuf[1];
  u16* bstg = bbuf[2];

  STAGE_ATTN(0, bcur);
  STAGE_ATTN(1, bnxt);
  __builtin_amdgcn_sched_barrier(0);
  asm volatile("s_waitcnt vmcnt(4) lgkmcnt(0)" ::: "memory");   // chunk 0 landed; tables visible
  __builtin_amdgcn_s_barrier();
  __builtin_amdgcn_sched_barrier(0);

#pragma unroll 1
  for (int mt = 0; mt < 14; ++mt) {
    STAGE_ATTN(mt + 2, bstg);
    COMPUTE_ATTN(mt, bcur);
    __builtin_amdgcn_sched_barrier(0);
    asm volatile("s_waitcnt vmcnt(4)" ::: "memory");            // chunk mt+1 landed; mt+2 in flight
    __builtin_amdgcn_s_barrier();
    __builtin_amdgcn_sched_barrier(0);
    u16* tmp = bcur; bcur = bnxt; bnxt = bstg; bstg = tmp;
  }
  COMPUTE_ATTN(14, bcur);
  __builtin_amdgcn_sched_barrier(0);
  asm volatile("s_waitcnt vmcnt(0)" ::: "memory");              // chunk 15 landed
  __builtin_amdgcn_s_barrier();
  __builtin_amdgcn_sched_barrier(0);
  COMPUTE_ATTN(15, bnxt);
#undef STAGE_ATTN
#undef COMPUTE_ATTN

  const float beta = betag[0];
  const float* invb = invg + b * 1024;
  const u16* hf = hbf + (size_t)b * 1024 * 512;
#pragma unroll
  for (int ct = 0; ct < 4; ++ct) {
    const int colv = c0 + ct * 32 + l31;
#pragma unroll
    for (int rg = 0; rg < 4; ++rg) {
      const int rowb = n0 + w * 32 + rg * 8 + lhi * 4;
      f32x4 iv = *reinterpret_cast<const f32x4*>(&invb[rowb]);
#pragma unroll
      for (int q = 0; q < 4; ++q) {
        float hv = bf2f(hf[(size_t)(rowb + q) * 512 + colv]);
        float xv = acc[ct][rg * 4 + q] * iv[q] + beta * hv;
        out[((size_t)b * 1024 + rowb + q) * 512 + colv] = xv > 0.f ? xv : __expf(xv) - 1.0f;
      }
    }
  }
}

extern "C" void kernel_launch(void* const* d_in, const int* in_sizes, int n_in,
                              void* d_out, int out_size, void* d_ws, size_t ws_size,
                              hipStream_t stream) {
  const float* x = (const float*)d_in[0];
  const float* W = (const float*)d_in[1];
  const float* a = (const float*)d_in[2];
  const float* beta = (const float*)d_in[3];
  float* out = (float*)d_out;

  char* ws = (char*)d_ws;
  u16* hbf = (u16*)ws;                              // 16 MB
  u16* hbt = (u16*)(ws + (16u << 20));              // 16 MB
  u16* wbt = (u16*)(ws + (32u << 20));              // 512 KB
  float* s1p = (float*)(ws + (32u << 20) + (512u << 10));   // 256 KB
  float* s2p = (float*)(ws + (32u << 20) + (768u << 10));   // 256 KB
  float* s1L = (float*)(ws + (33u << 20));          // 64 KB
  float* s2L = (float*)(ws + (33u << 20) + (64u << 10));
  float* inv = (float*)(ws + (33u << 20) + (128u << 10));

  k_cast_wT<<<1024, 256, 0, stream>>>(W, wbt);
  k_gemm1<<<512, 256, 0, stream>>>(x, wbt, a, hbf, hbt, s1p, s2p);
  k_reduce<<<64, 256, 0, stream>>>(s1p, s2p, s1L, s2L);
  k_denom<<<4096, 256, 0, stream>>>(s1L, s2L, inv);
  k_attn<<<512, 256, 0, stream>>>(hbt, hbf, s1L, s2L, inv, beta, out);
}

// Round 7
// 71.511 us; speedup vs baseline: 2.5601x; 1.0431x over previous
//
#include <hip/hip_runtime.h>

using u16 = unsigned short;
using u32 = unsigned int;

#define ALPHA 0.2f
#define LOG2E 1.4426950408889634f

typedef __bf16 bf16x8 __attribute__((ext_vector_type(8)));
typedef float f32x4 __attribute__((ext_vector_type(4)));
typedef float f32x16 __attribute__((ext_vector_type(16)));

__device__ __forceinline__ u16 f2bf(float f) {
  u32 u = __builtin_bit_cast(u32, f);
  u += 0x7FFFu + ((u >> 16) & 1u);   // RTNE
  return (u16)(u >> 16);
}
__device__ __forceinline__ float bf2f(u16 h) {
  u32 u = ((u32)h) << 16;
  return __builtin_bit_cast(float, u);
}
__device__ __forceinline__ void gload_lds16(const void* g, void* l) {
  __builtin_amdgcn_global_load_lds((__attribute__((address_space(1))) void*)g,
                                   (__attribute__((address_space(3))) void*)l,
                                   16, 0, 0);
}

// ---------- cast+transpose W: wbt[n][k] = bf16(W[k][n]) ----------
__global__ __launch_bounds__(256) void k_cast_wT(const float* __restrict__ W, u16* __restrict__ wbt) {
  int idx = blockIdx.x * 256 + threadIdx.x;
  int k = idx >> 9, n = idx & 511;
  wbt[n * 512 + k] = f2bf(W[idx]);
}

// hbt2 tiled layout (u16 elems, per batch 512K):
//   IDX(m,f) = (m>>4)*8192 + (f>>5)*512 + ((m>>3)&1)*256 + (f&31)*8 + (m&7)
// -> a wave's 32x32x16 B-fragment (16 m x 32 f) is 64 consecutive 16B granules.

// ---------- gemm1: h = x@W (M=16384,K=512,N=512). 128x128 tile, 4 waves.
// Triple-buffered, counted vmcnt. XCD-swizzled so the 4 cb-blocks of a tile_m
// share an XCD (x-row L2 reuse). Epilogue: lT -> hbf + hbt2(tiled) + score partials.
__global__ __launch_bounds__(256, 2) void k_gemm1(const float* __restrict__ x, const u16* __restrict__ wbt,
                                                  const float* __restrict__ a,
                                                  u16* __restrict__ hbf, u16* __restrict__ hbt2,
                                                  float* __restrict__ s1p, float* __restrict__ s2p) {
  __shared__ __attribute__((aligned(16))) char lds[73728];
  __shared__ __attribute__((aligned(16))) float a_l[256];

  const int t = threadIdx.x;
  const int lane = t & 63;
  const int w = t >> 6;
  const int l31 = lane & 31, lhi = lane >> 5;
  const int rb = w >> 1, cg = w & 1;
  // XCD swizzle: blocks {g, g+8, g+16, g+24} (same XCD under i%8 dispatch) share tile_m
  const int g = blockIdx.x;
  const int cb = (g >> 3) & 3;
  const int tile_m = (g & 7) | ((g >> 5) << 3);
  const int row0 = tile_m * 128;
  const int col0 = cb * 128;

  a_l[t] = (t < 128) ? a[col0 + t] : a[512 + col0 + (t - 128)];

  f32x16 acc[2][2];
#pragma unroll
  for (int i = 0; i < 2; ++i)
#pragma unroll
    for (int j = 0; j < 2; ++j)
#pragma unroll
      for (int r = 0; r < 16; ++r) acc[i][j][r] = 0.f;

#define STAGE_G1(kt, Ab, Bb)                                                              \
  {                                                                                       \
    const int k0_ = (kt) * 32;                                                            \
    _Pragma("unroll")                                                                     \
    for (int i = 0; i < 4; ++i) {                                                         \
      int G = i * 256 + t;                                                                \
      int row = G >> 3, ks = G & 7;                                                       \
      gload_lds16(x + (size_t)(row0 + row) * 512 + k0_ + ((ks ^ (row & 7)) * 4),          \
                  (Ab) + (size_t)(i * 256 + w * 64) * 16);                                \
    }                                                                                     \
    _Pragma("unroll")                                                                     \
    for (int i = 0; i < 2; ++i) {                                                         \
      int G = i * 256 + t;                                                                \
      int col = G >> 2, ks = G & 3;                                                       \
      gload_lds16(wbt + (size_t)(col0 + col) * 512 + k0_ + ((ks ^ ((col >> 1) & 3)) * 8), \
                  (Bb) + (size_t)(i * 256 + w * 64) * 16);                                \
    }                                                                                     \
  }

#define COMPUTE_G1(Ab, Bb)                                                                         \
  {                                                                                                \
    _Pragma("unroll")                                                                              \
    for (int ks = 0; ks < 2; ++ks) {                                                               \
      bf16x8 af[2];                                                                                \
      _Pragma("unroll")                                                                            \
      for (int sub = 0; sub < 2; ++sub) {                                                          \
        const int arow = rb * 64 + sub * 32 + l31;                                                 \
        const int kg = ks * 4 + lhi * 2;                                                           \
        f32x4 fa0 = *reinterpret_cast<const f32x4*>((Ab) + (size_t)(arow * 8 + (kg ^ (arow & 7))) * 16); \
        f32x4 fa1 = *reinterpret_cast<const f32x4*>((Ab) + (size_t)(arow * 8 + ((kg + 1) ^ (arow & 7))) * 16); \
        _Pragma("unroll")                                                                          \
        for (int jj = 0; jj < 4; ++jj) {                                                           \
          af[sub][jj] = (__bf16)fa0[jj];                                                           \
          af[sub][jj + 4] = (__bf16)fa1[jj];                                                       \
        }                                                                                          \
      }                                                                                            \
      bf16x8 bfr[2];                                                                               \
      _Pragma("unroll")                                                                            \
      for (int bt = 0; bt < 2; ++bt) {                                                             \
        const int bcol = cg * 64 + bt * 32 + l31;                                                  \
        const int kslot = (ks * 2 + lhi) ^ ((bcol >> 1) & 3);                                      \
        bfr[bt] = *reinterpret_cast<const bf16x8*>((Bb) + (size_t)(bcol * 4 + kslot) * 16);        \
      }                                                                                            \
      _Pragma("unroll")                                                                            \
      for (int sub = 0; sub < 2; ++sub)                                                            \
        _Pragma("unroll")                                                                          \
        for (int bt = 0; bt < 2; ++bt)                                                             \
          acc[sub][bt] = __builtin_amdgcn_mfma_f32_32x32x16_bf16(af[sub], bfr[bt], acc[sub][bt], 0, 0, 0); \
    }                                                                                              \
  }

  char* Ac = lds;             char* Bc = lds + 49152;
  char* An = lds + 16384;     char* Bn = lds + 57344;
  char* As = lds + 32768;     char* Bs = lds + 65536;

  STAGE_G1(0, Ac, Bc);
  STAGE_G1(1, An, Bn);
  __builtin_amdgcn_sched_barrier(0);
  asm volatile("s_waitcnt vmcnt(6) lgkmcnt(0)" ::: "memory");
  __builtin_amdgcn_s_barrier();
  __builtin_amdgcn_sched_barrier(0);

#pragma unroll 1
  for (int kt = 0; kt < 14; ++kt) {
    STAGE_G1(kt + 2, As, Bs);
    COMPUTE_G1(Ac, Bc);
    __builtin_amdgcn_sched_barrier(0);
    asm volatile("s_waitcnt vmcnt(6)" ::: "memory");
    __builtin_amdgcn_s_barrier();
    __builtin_amdgcn_sched_barrier(0);
    char* ta = Ac; Ac = An; An = As; As = ta;
    char* tb = Bc; Bc = Bn; Bn = Bs; Bs = tb;
  }
  COMPUTE_G1(Ac, Bc);
  __builtin_amdgcn_sched_barrier(0);
  asm volatile("s_waitcnt vmcnt(0)" ::: "memory");
  __builtin_amdgcn_s_barrier();
  __builtin_amdgcn_sched_barrier(0);
  COMPUTE_G1(An, Bn);
#undef STAGE_G1
#undef COMPUTE_G1

  __syncthreads();

  // epilogue: frags -> lT [128][136]
  u16* lT = (u16*)lds;
#pragma unroll
  for (int sub = 0; sub < 2; ++sub)
#pragma unroll
    for (int bt = 0; bt < 2; ++bt) {
      const int col = cg * 64 + bt * 32 + l31;
#pragma unroll
      for (int r = 0; r < 16; ++r) {
        int row = rb * 64 + sub * 32 + (r & 3) + 8 * (r >> 2) + 4 * lhi;
        lT[row * 136 + col] = f2bf(acc[sub][bt][r]);
      }
    }
  __syncthreads();

  // hbf: [row][col] coalesced (2048 granules)
#pragma unroll
  for (int i = 0; i < 8; ++i) {
    int G = i * 256 + t;
    int row = G >> 4, gg = G & 15;
    uint4 v = *reinterpret_cast<const uint4*>(&lT[row * 136 + gg * 8]);
    *reinterpret_cast<uint4*>(&hbf[(size_t)(row0 + row) * 512 + col0 + gg * 8]) = v;
  }
  // hbt2: tiled fragment layout
  const int bb = row0 >> 10;
  const int nb = row0 & 1023;
  u16* hb2 = hbt2 + (size_t)bb * 524288;
#pragma unroll
  for (int i = 0; i < 8; ++i) {
    int G = i * 256 + t;
    int col = G & 127, rg = G >> 7;
    u32 wd[4];
#pragma unroll
    for (int jj = 0; jj < 4; ++jj) {
      u16 lo = lT[(rg * 8 + 2 * jj) * 136 + col];
      u16 hi = lT[(rg * 8 + 2 * jj + 1) * 136 + col];
      wd[jj] = (u32)lo | ((u32)hi << 16);
    }
    uint4 o = {wd[0], wd[1], wd[2], wd[3]};
    const int m0 = nb + rg * 8;
    const int f = col0 + col;
    size_t idx = (size_t)(m0 >> 4) * 8192 + (size_t)(f >> 5) * 512 + (size_t)((m0 >> 3) & 1) * 256 + (size_t)(f & 31) * 8;
    *reinterpret_cast<uint4*>(&hb2[idx]) = o;
  }
  // score partials
  {
    const int r2 = t >> 1, half = t & 1;
    float d1 = 0.f, d2 = 0.f;
#pragma unroll
    for (int i = 0; i < 8; ++i) {
      uint4 v = *reinterpret_cast<const uint4*>(&lT[r2 * 136 + half * 64 + i * 8]);
      u32 wds[4] = {v.x, v.y, v.z, v.w};
#pragma unroll
      for (int jj = 0; jj < 8; ++jj) {
        float h = bf2f((u16)(wds[jj >> 1] >> ((jj & 1) * 16)));
        d1 += h * a_l[half * 64 + i * 8 + jj];
        d2 += h * a_l[128 + half * 64 + i * 8 + jj];
      }
    }
    d1 += __shfl_xor(d1, 1);
    d2 += __shfl_xor(d2, 1);
    if (half == 0) {
      s1p[cb * 16384 + row0 + r2] = d1;
      s2p[cb * 16384 + row0 + r2] = d2;
    }
  }
}

// ---------- reduce score partials -> s1L, s2L (scaled by log2e) ----------
__global__ __launch_bounds__(256) void k_reduce(const float* __restrict__ s1p, const float* __restrict__ s2p,
                                                float* __restrict__ s1L, float* __restrict__ s2L) {
  int id = blockIdx.x * 256 + threadIdx.x;
  float d1 = s1p[id] + s1p[16384 + id] + s1p[32768 + id] + s1p[49152 + id];
  float d2 = s2p[id] + s2p[16384 + id] + s2p[32768 + id] + s2p[49152 + id];
  s1L[id] = d1 * LOG2E;
  s2L[id] = d2 * LOG2E;
}

// ---------- attn: barrier-free PV GEMM. B-frags coalesced from L2-resident hbt2;
// P in-register via rank-1 tables; denom accumulated in-loop (k_denom eliminated). ----------
__global__ __launch_bounds__(256, 2) void k_attn(const u16* __restrict__ hbt2, const u16* __restrict__ hbf,
                                                 const float* __restrict__ s1Lg, const float* __restrict__ s2Lg,
                                                 const float* __restrict__ betag, float* __restrict__ out) {
  __shared__ __attribute__((aligned(16))) float e1_l[1024];
  __shared__ __attribute__((aligned(16))) float e2_l[1024];
  __shared__ __attribute__((aligned(16))) float inv_l[128];
  const int t = threadIdx.x;
  const int lane = t & 63;
  const int w = t >> 6;
  const int l31 = lane & 31, lhi = lane >> 5;

  const int B = blockIdx.x;
  const int b = (B & 7) * 2 + ((B >> 3) & 1);   // XCD swizzle: 2 batches/XCD L2
  const int j = B >> 4;                          // 0..31
  const int n0 = (j >> 2) * 128;
  const int c0 = (j & 3) * 128;

  const u16* hb2 = hbt2 + (size_t)b * 524288;

  for (int i = t; i < 1024; i += 256) {
    float v = s2Lg[b * 1024 + i];
    e1_l[i] = exp2f(v);
    e2_l[i] = exp2f(ALPHA * v);
  }

  const int myrow = n0 + w * 32 + l31;
  const float s1v = s1Lg[b * 1024 + myrow];
  const float c1 = exp2f(s1v), c2 = exp2f(ALPHA * s1v);

  f32x16 acc[4];
#pragma unroll
  for (int ct = 0; ct < 4; ++ct)
#pragma unroll
    for (int r = 0; r < 16; ++r) acc[ct][r] = 0.f;
  float psum = 0.f;

  __syncthreads();   // tables visible

  const u16* bp = hb2 + (size_t)(c0 >> 5) * 512 + (size_t)(lhi * 32 + l31) * 8;

#define STEP_ATTN(s, buf)                                                      \
  {                                                                            \
    const int mo = (s) * 16 + lhi * 8;                                         \
    f32x4 ea = *reinterpret_cast<const f32x4*>(&e1_l[mo]);                     \
    f32x4 eb = *reinterpret_cast<const f32x4*>(&e1_l[mo + 4]);                 \
    f32x4 fa = *reinterpret_cast<const f32x4*>(&e2_l[mo]);                     \
    f32x4 fb = *reinterpret_cast<const f32x4*>(&e2_l[mo + 4]);                 \
    bf16x8 af;                                                                 \
    _Pragma("unroll")                                                          \
    for (int q = 0; q < 4; ++q) {                                              \
      float p0 = fmaxf(c1 * ea[q], c2 * fa[q]);                                \
      float p1 = fmaxf(c1 * eb[q], c2 * fb[q]);                                \
      psum += p0 + p1;                                                         \
      af[q] = (__bf16)p0;                                                      \
      af[q + 4] = (__bf16)p1;                                                  \
    }                                                                          \
    _Pragma("unroll")                                                          \
    for (int ct = 0; ct < 4; ++ct)                                             \
      acc[ct] = __builtin_amdgcn_mfma_f32_32x32x16_bf16(af, (buf)[ct], acc[ct], 0, 0, 0); \
  }

  bf16x8 bv[4];
#pragma unroll
  for (int ct = 0; ct < 4; ++ct) bv[ct] = *reinterpret_cast<const bf16x8*>(bp + ct * 512);

#pragma unroll 4
  for (int s = 0; s < 63; ++s) {
    bf16x8 nv[4];
    const u16* np = bp + (size_t)(s + 1) * 8192;
#pragma unroll
    for (int ct = 0; ct < 4; ++ct) nv[ct] = *reinterpret_cast<const bf16x8*>(np + ct * 512);
    STEP_ATTN(s, bv);
#pragma unroll
    for (int ct = 0; ct < 4; ++ct) bv[ct] = nv[ct];
  }
  STEP_ATTN(63, bv);
#undef STEP_ATTN

  // denom: lane pair (l31, l31+32) covers all 1024 m for row myrow
  psum += __shfl_xor(psum, 32);
  if (lhi == 0) inv_l[w * 32 + l31] = 1.0f / psum;
  __syncthreads();

  const float beta = betag[0];
  const u16* hf = hbf + (size_t)b * 1024 * 512;
#pragma unroll
  for (int ct = 0; ct < 4; ++ct) {
    const int colv = c0 + ct * 32 + l31;
#pragma unroll
    for (int rg = 0; rg < 4; ++rg) {
      const int rl = rg * 8 + lhi * 4;
      const int rowb = n0 + w * 32 + rl;
      f32x4 iv = *reinterpret_cast<const f32x4*>(&inv_l[w * 32 + rl]);
#pragma unroll
      for (int q = 0; q < 4; ++q) {
        float hv = bf2f(hf[(size_t)(rowb + q) * 512 + colv]);
        float xv = acc[ct][rg * 4 + q] * iv[q] + beta * hv;
        out[((size_t)b * 1024 + rowb + q) * 512 + colv] = xv > 0.f ? xv : __expf(xv) - 1.0f;
      }
    }
  }
}

extern "C" void kernel_launch(void* const* d_in, const int* in_sizes, int n_in,
                              void* d_out, int out_size, void* d_ws, size_t ws_size,
                              hipStream_t stream) {
  const float* x = (const float*)d_in[0];
  const float* W = (const float*)d_in[1];
  const float* a = (const float*)d_in[2];
  const float* beta = (const float*)d_in[3];
  float* out = (float*)d_out;

  char* ws = (char*)d_ws;
  u16* hbf = (u16*)ws;                              // 16 MB
  u16* hbt2 = (u16*)(ws + (16u << 20));             // 16 MB, tiled layout
  u16* wbt = (u16*)(ws + (32u << 20));              // 512 KB
  float* s1p = (float*)(ws + (32u << 20) + (512u << 10));   // 256 KB
  float* s2p = (float*)(ws + (32u << 20) + (768u << 10));   // 256 KB
  float* s1L = (float*)(ws + (33u << 20));          // 64 KB
  float* s2L = (float*)(ws + (33u << 20) + (64u << 10));

  k_cast_wT<<<1024, 256, 0, stream>>>(W, wbt);
  k_gemm1<<<512, 256, 0, stream>>>(x, wbt, a, hbf, hbt2, s1p, s2p);
  k_reduce<<<64, 256, 0, stream>>>(s1p, s2p, s1L, s2L);
  k_attn<<<512, 256, 0, stream>>>(hbt2, hbf, s1L, s2L, beta, out);
}

// Round 8
// 62.484 us; speedup vs baseline: 2.9299x; 1.1445x over previous
//
#include <hip/hip_runtime.h>

using u16 = unsigned short;
using u32 = unsigned int;

#define ALPHA 0.2f
#define LOG2E 1.4426950408889634f

typedef __bf16 bf16x8 __attribute__((ext_vector_type(8)));
typedef float f32x4 __attribute__((ext_vector_type(4)));
typedef float f32x16 __attribute__((ext_vector_type(16)));

__device__ __forceinline__ u16 f2bf(float f) {
  u32 u = __builtin_bit_cast(u32, f);
  u += 0x7FFFu + ((u >> 16) & 1u);   // RTNE
  return (u16)(u >> 16);
}
__device__ __forceinline__ float bf2f(u16 h) {
  u32 u = ((u32)h) << 16;
  return __builtin_bit_cast(float, u);
}
__device__ __forceinline__ void gload_lds16(const void* g, void* l) {
  __builtin_amdgcn_global_load_lds((__attribute__((address_space(1))) void*)g,
                                   (__attribute__((address_space(3))) void*)l,
                                   16, 0, 0);
}

// ---------- cast+transpose W: wbt[n][k] = bf16(W[k][n]) ----------
__global__ __launch_bounds__(256) void k_cast_wT(const float* __restrict__ W, u16* __restrict__ wbt) {
  int idx = blockIdx.x * 256 + threadIdx.x;
  int k = idx >> 9, n = idx & 511;
  wbt[n * 512 + k] = f2bf(W[idx]);
}

// hbt2 tiled layout (u16 elems, per batch 512K):
//   IDX(m,f) = (m>>4)*8192 + (f>>5)*512 + ((m>>3)&1)*256 + (f&31)*8 + (m&7)
// -> a wave's 32x32x16 B-fragment (16 m x 32 f) is 64 consecutive 16B granules.

// ---------- gemm1: h = x@W (M=16384,K=512,N=512). 128x128 tile, 4 waves.
// Triple-buffered, counted vmcnt. XCD-swizzled so the 4 cb-blocks of a tile_m
// share an XCD (x-row L2 reuse). Epilogue: lT -> hbf + hbt2(tiled) + score partials.
__global__ __launch_bounds__(256, 2) void k_gemm1(const float* __restrict__ x, const u16* __restrict__ wbt,
                                                  const float* __restrict__ a,
                                                  u16* __restrict__ hbf, u16* __restrict__ hbt2,
                                                  float* __restrict__ s1p, float* __restrict__ s2p) {
  __shared__ __attribute__((aligned(16))) char lds[73728];
  __shared__ __attribute__((aligned(16))) float a_l[256];

  const int t = threadIdx.x;
  const int lane = t & 63;
  const int w = t >> 6;
  const int l31 = lane & 31, lhi = lane >> 5;
  const int rb = w >> 1, cg = w & 1;
  const int g = blockIdx.x;
  const int cb = (g >> 3) & 3;
  const int tile_m = (g & 7) | ((g >> 5) << 3);
  const int row0 = tile_m * 128;
  const int col0 = cb * 128;

  a_l[t] = (t < 128) ? a[col0 + t] : a[512 + col0 + (t - 128)];

  f32x16 acc[2][2];
#pragma unroll
  for (int i = 0; i < 2; ++i)
#pragma unroll
    for (int j = 0; j < 2; ++j)
#pragma unroll
      for (int r = 0; r < 16; ++r) acc[i][j][r] = 0.f;

#define STAGE_G1(kt, Ab, Bb)                                                              \
  {                                                                                       \
    const int k0_ = (kt) * 32;                                                            \
    _Pragma("unroll")                                                                     \
    for (int i = 0; i < 4; ++i) {                                                         \
      int G = i * 256 + t;                                                                \
      int row = G >> 3, ks = G & 7;                                                       \
      gload_lds16(x + (size_t)(row0 + row) * 512 + k0_ + ((ks ^ (row & 7)) * 4),          \
                  (Ab) + (size_t)(i * 256 + w * 64) * 16);                                \
    }                                                                                     \
    _Pragma("unroll")                                                                     \
    for (int i = 0; i < 2; ++i) {                                                         \
      int G = i * 256 + t;                                                                \
      int col = G >> 2, ks = G & 3;                                                       \
      gload_lds16(wbt + (size_t)(col0 + col) * 512 + k0_ + ((ks ^ ((col >> 1) & 3)) * 8), \
                  (Bb) + (size_t)(i * 256 + w * 64) * 16);                                \
    }                                                                                     \
  }

#define COMPUTE_G1(Ab, Bb)                                                                         \
  {                                                                                                \
    _Pragma("unroll")                                                                              \
    for (int ks = 0; ks < 2; ++ks) {                                                               \
      bf16x8 af[2];                                                                                \
      _Pragma("unroll")                                                                            \
      for (int sub = 0; sub < 2; ++sub) {                                                          \
        const int arow = rb * 64 + sub * 32 + l31;                                                 \
        const int kg = ks * 4 + lhi * 2;                                                           \
        f32x4 fa0 = *reinterpret_cast<const f32x4*>((Ab) + (size_t)(arow * 8 + (kg ^ (arow & 7))) * 16); \
        f32x4 fa1 = *reinterpret_cast<const f32x4*>((Ab) + (size_t)(arow * 8 + ((kg + 1) ^ (arow & 7))) * 16); \
        _Pragma("unroll")                                                                          \
        for (int jj = 0; jj < 4; ++jj) {                                                           \
          af[sub][jj] = (__bf16)fa0[jj];                                                           \
          af[sub][jj + 4] = (__bf16)fa1[jj];                                                       \
        }                                                                                          \
      }                                                                                            \
      bf16x8 bfr[2];                                                                               \
      _Pragma("unroll")                                                                            \
      for (int bt = 0; bt < 2; ++bt) {                                                             \
        const int bcol = cg * 64 + bt * 32 + l31;                                                  \
        const int kslot = (ks * 2 + lhi) ^ ((bcol >> 1) & 3);                                      \
        bfr[bt] = *reinterpret_cast<const bf16x8*>((Bb) + (size_t)(bcol * 4 + kslot) * 16);        \
      }                                                                                            \
      _Pragma("unroll")                                                                            \
      for (int sub = 0; sub < 2; ++sub)                                                            \
        _Pragma("unroll")                                                                          \
        for (int bt = 0; bt < 2; ++bt)                                                             \
          acc[sub][bt] = __builtin_amdgcn_mfma_f32_32x32x16_bf16(af[sub], bfr[bt], acc[sub][bt], 0, 0, 0); \
    }                                                                                              \
  }

  char* Ac = lds;             char* Bc = lds + 49152;
  char* An = lds + 16384;     char* Bn = lds + 57344;
  char* As = lds + 32768;     char* Bs = lds + 65536;

  STAGE_G1(0, Ac, Bc);
  STAGE_G1(1, An, Bn);
  __builtin_amdgcn_sched_barrier(0);
  asm volatile("s_waitcnt vmcnt(6) lgkmcnt(0)" ::: "memory");
  __builtin_amdgcn_s_barrier();
  __builtin_amdgcn_sched_barrier(0);

#pragma unroll 1
  for (int kt = 0; kt < 14; ++kt) {
    STAGE_G1(kt + 2, As, Bs);
    COMPUTE_G1(Ac, Bc);
    __builtin_amdgcn_sched_barrier(0);
    asm volatile("s_waitcnt vmcnt(6)" ::: "memory");
    __builtin_amdgcn_s_barrier();
    __builtin_amdgcn_sched_barrier(0);
    char* ta = Ac; Ac = An; An = As; As = ta;
    char* tb = Bc; Bc = Bn; Bn = Bs; Bs = tb;
  }
  COMPUTE_G1(Ac, Bc);
  __builtin_amdgcn_sched_barrier(0);
  asm volatile("s_waitcnt vmcnt(0)" ::: "memory");
  __builtin_amdgcn_s_barrier();
  __builtin_amdgcn_sched_barrier(0);
  COMPUTE_G1(An, Bn);
#undef STAGE_G1
#undef COMPUTE_G1

  __syncthreads();

  // epilogue: frags -> lT [128][136]
  u16* lT = (u16*)lds;
#pragma unroll
  for (int sub = 0; sub < 2; ++sub)
#pragma unroll
    for (int bt = 0; bt < 2; ++bt) {
      const int col = cg * 64 + bt * 32 + l31;
#pragma unroll
      for (int r = 0; r < 16; ++r) {
        int row = rb * 64 + sub * 32 + (r & 3) + 8 * (r >> 2) + 4 * lhi;
        lT[row * 136 + col] = f2bf(acc[sub][bt][r]);
      }
    }
  __syncthreads();

  // hbf: [row][col] coalesced (2048 granules)
#pragma unroll
  for (int i = 0; i < 8; ++i) {
    int G = i * 256 + t;
    int row = G >> 4, gg = G & 15;
    uint4 v = *reinterpret_cast<const uint4*>(&lT[row * 136 + gg * 8]);
    *reinterpret_cast<uint4*>(&hbf[(size_t)(row0 + row) * 512 + col0 + gg * 8]) = v;
  }
  // hbt2: tiled fragment layout
  const int bb = row0 >> 10;
  const int nb = row0 & 1023;
  u16* hb2 = hbt2 + (size_t)bb * 524288;
#pragma unroll
  for (int i = 0; i < 8; ++i) {
    int G = i * 256 + t;
    int col = G & 127, rg = G >> 7;
    u32 wd[4];
#pragma unroll
    for (int jj = 0; jj < 4; ++jj) {
      u16 lo = lT[(rg * 8 + 2 * jj) * 136 + col];
      u16 hi = lT[(rg * 8 + 2 * jj + 1) * 136 + col];
      wd[jj] = (u32)lo | ((u32)hi << 16);
    }
    uint4 o = {wd[0], wd[1], wd[2], wd[3]};
    const int m0 = nb + rg * 8;
    const int f = col0 + col;
    size_t idx = (size_t)(m0 >> 4) * 8192 + (size_t)(f >> 5) * 512 + (size_t)((m0 >> 3) & 1) * 256 + (size_t)(f & 31) * 8;
    *reinterpret_cast<uint4*>(&hb2[idx]) = o;
  }
  // score partials
  {
    const int r2 = t >> 1, half = t & 1;
    float d1 = 0.f, d2 = 0.f;
#pragma unroll
    for (int i = 0; i < 8; ++i) {
      uint4 v = *reinterpret_cast<const uint4*>(&lT[r2 * 136 + half * 64 + i * 8]);
      u32 wds[4] = {v.x, v.y, v.z, v.w};
#pragma unroll
      for (int jj = 0; jj < 8; ++jj) {
        float h = bf2f((u16)(wds[jj >> 1] >> ((jj & 1) * 16)));
        d1 += h * a_l[half * 64 + i * 8 + jj];
        d2 += h * a_l[128 + half * 64 + i * 8 + jj];
      }
    }
    d1 += __shfl_xor(d1, 1);
    d2 += __shfl_xor(d2, 1);
    if (half == 0) {
      s1p[cb * 16384 + row0 + r2] = d1;
      s2p[cb * 16384 + row0 + r2] = d2;
    }
  }
}

// ---------- reduce score partials -> s1L, s2L (scaled by log2e) ----------
__global__ __launch_bounds__(256) void k_reduce(const float* __restrict__ s1p, const float* __restrict__ s2p,
                                                float* __restrict__ s1L, float* __restrict__ s2L) {
  int id = blockIdx.x * 256 + threadIdx.x;
  float d1 = s1p[id] + s1p[16384 + id] + s1p[32768 + id] + s1p[49152 + id];
  float d2 = s2p[id] + s2p[16384 + id] + s2p[32768 + id] + s2p[49152 + id];
  s1L[id] = d1 * LOG2E;
  s2L[id] = d2 * LOG2E;
}

// ---------- attn: barrier-free PV GEMM, depth-4 register pipeline on B-frags.
// B-frags coalesced from L2-resident hbt2; P in-register; denom in-loop. ----------
__global__ __launch_bounds__(256, 2) void k_attn(const u16* __restrict__ hbt2, const u16* __restrict__ hbf,
                                                 const float* __restrict__ s1Lg, const float* __restrict__ s2Lg,
                                                 const float* __restrict__ betag, float* __restrict__ out) {
  __shared__ __attribute__((aligned(16))) float e1_l[1024];
  __shared__ __attribute__((aligned(16))) float e2_l[1024];
  __shared__ __attribute__((aligned(16))) float inv_l[128];
  const int t = threadIdx.x;
  const int lane = t & 63;
  const int w = t >> 6;
  const int l31 = lane & 31, lhi = lane >> 5;

  const int B = blockIdx.x;
  const int b = (B & 7) * 2 + ((B >> 3) & 1);   // XCD swizzle: 2 batches/XCD L2
  const int j = B >> 4;                          // 0..31
  const int n0 = (j >> 2) * 128;
  const int c0 = (j & 3) * 128;

  const u16* hb2 = hbt2 + (size_t)b * 524288;

  for (int i = t; i < 1024; i += 256) {
    float v = s2Lg[b * 1024 + i];
    e1_l[i] = exp2f(v);
    e2_l[i] = exp2f(ALPHA * v);
  }

  const int myrow = n0 + w * 32 + l31;
  const float s1v = s1Lg[b * 1024 + myrow];
  const float c1 = exp2f(s1v), c2 = exp2f(ALPHA * s1v);

  f32x16 acc[4];
#pragma unroll
  for (int ct = 0; ct < 4; ++ct)
#pragma unroll
    for (int r = 0; r < 16; ++r) acc[ct][r] = 0.f;
  float psum = 0.f;

  __syncthreads();   // tables visible

  const u16* bp = hb2 + (size_t)(c0 >> 5) * 512 + (size_t)(lhi * 32 + l31) * 8;

#define LOAD_B(dst, s)                                                                        \
  {                                                                                           \
    const u16* np_ = bp + (size_t)(s) * 8192;                                                 \
    _Pragma("unroll")                                                                         \
    for (int ct = 0; ct < 4; ++ct) dst[ct] = *reinterpret_cast<const bf16x8*>(np_ + ct * 512); \
  }

#define STEP_ATTN(s, buf)                                                      \
  {                                                                            \
    const int mo = (s) * 16 + lhi * 8;                                         \
    f32x4 ea = *reinterpret_cast<const f32x4*>(&e1_l[mo]);                     \
    f32x4 eb = *reinterpret_cast<const f32x4*>(&e1_l[mo + 4]);                 \
    f32x4 fa = *reinterpret_cast<const f32x4*>(&e2_l[mo]);                     \
    f32x4 fb = *reinterpret_cast<const f32x4*>(&e2_l[mo + 4]);                 \
    bf16x8 af;                                                                 \
    _Pragma("unroll")                                                          \
    for (int q = 0; q < 4; ++q) {                                              \
      float p0 = fmaxf(c1 * ea[q], c2 * fa[q]);                                \
      float p1 = fmaxf(c1 * eb[q], c2 * fb[q]);                                \
      psum += p0 + p1;                                                         \
      af[q] = (__bf16)p0;                                                      \
      af[q + 4] = (__bf16)p1;                                                  \
    }                                                                          \
    _Pragma("unroll")                                                          \
    for (int ct = 0; ct < 4; ++ct)                                             \
      acc[ct] = __builtin_amdgcn_mfma_f32_32x32x16_bf16(af, (buf)[ct], acc[ct], 0, 0, 0); \
  }

  // depth-4 static register pipeline: 16 B-loads in flight, ~3 steps of latency cover
  bf16x8 p0[4], p1[4], p2[4], p3[4];
  LOAD_B(p0, 0);
  LOAD_B(p1, 1);
  LOAD_B(p2, 2);
  LOAD_B(p3, 3);

#pragma unroll 1
  for (int s = 0; s < 60; s += 4) {
    STEP_ATTN(s + 0, p0); LOAD_B(p0, s + 4);
    STEP_ATTN(s + 1, p1); LOAD_B(p1, s + 5);
    STEP_ATTN(s + 2, p2); LOAD_B(p2, s + 6);
    STEP_ATTN(s + 3, p3); LOAD_B(p3, s + 7);
  }
  STEP_ATTN(60, p0);
  STEP_ATTN(61, p1);
  STEP_ATTN(62, p2);
  STEP_ATTN(63, p3);
#undef LOAD_B
#undef STEP_ATTN

  // denom: lane pair (l31, l31+32) covers all 1024 m for row myrow
  psum += __shfl_xor(psum, 32);
  if (lhi == 0) inv_l[w * 32 + l31] = 1.0f / psum;
  __syncthreads();

  const float beta = betag[0];
  const u16* hf = hbf + (size_t)b * 1024 * 512;
#pragma unroll
  for (int ct = 0; ct < 4; ++ct) {
    const int colv = c0 + ct * 32 + l31;
#pragma unroll
    for (int rg = 0; rg < 4; ++rg) {
      const int rl = rg * 8 + lhi * 4;
      const int rowb = n0 + w * 32 + rl;
      f32x4 iv = *reinterpret_cast<const f32x4*>(&inv_l[w * 32 + rl]);
#pragma unroll
      for (int q = 0; q < 4; ++q) {
        float hv = bf2f(hf[(size_t)(rowb + q) * 512 + colv]);
        float xv = acc[ct][rg * 4 + q] * iv[q] + beta * hv;
        out[((size_t)b * 1024 + rowb + q) * 512 + colv] = xv > 0.f ? xv : __expf(xv) - 1.0f;
      }
    }
  }
}

extern "C" void kernel_launch(void* const* d_in, const int* in_sizes, int n_in,
                              void* d_out, int out_size, void* d_ws, size_t ws_size,
                              hipStream_t stream) {
  const float* x = (const float*)d_in[0];
  const float* W = (const float*)d_in[1];
  const float* a = (const float*)d_in[2];
  const float* beta = (const float*)d_in[3];
  float* out = (float*)d_out;

  char* ws = (char*)d_ws;
  u16* hbf = (u16*)ws;                              // 16 MB
  u16* hbt2 = (u16*)(ws + (16u << 20));             // 16 MB, tiled layout
  u16* wbt = (u16*)(ws + (32u << 20));              // 512 KB
  float* s1p = (float*)(ws + (32u << 20) + (512u << 10));   // 256 KB
  float* s2p = (float*)(ws + (32u << 20) + (768u << 10));   // 256 KB
  float* s1L = (float*)(ws + (33u << 20));          // 64 KB
  float* s2L = (float*)(ws + (33u << 20) + (64u << 10));

  k_cast_wT<<<1024, 256, 0, stream>>>(W, wbt);
  k_gemm1<<<512, 256, 0, stream>>>(x, wbt, a, hbf, hbt2, s1p, s2p);
  k_reduce<<<64, 256, 0, stream>>>(s1p, s2p, s1L, s2L);
  k_attn<<<512, 256, 0, stream>>>(hbt2, hbf, s1L, s2L, beta, out);
}